// Round 11
// baseline (520.476 us; speedup 1.0000x reference)
//
#include <hip/hip_runtime.h>

constexpr int Nn = 100000;   // nodes
constexpr int Ee = 600000;   // edges
constexpr int Dd = 128;      // hidden dim
constexpr int Ll = 3;        // DAG layers
constexpr int Gg = 256;      // graphs
constexpr int Tt = 10;       // outputs per graph
constexpr float BN_EPS = 1e-5f;
constexpr int NREP = 128;    // stats replicas (slot = [128][512] floats)
constexpr int PSL = 8;       // pool slices per graph
constexpr int PR = 32;       // counting-sort bucket replicas per graph

typedef __attribute__((ext_vector_type(8))) short short8v;
typedef __attribute__((ext_vector_type(4))) float f32x4;

__device__ inline ushort bf_hi(float f) {
  unsigned u = __float_as_uint(f);
  unsigned r = (u + 0x7FFFu + ((u >> 16) & 1u)) >> 16;
  return (ushort)r;
}
__device__ inline float bf_f(ushort h) {
  return __uint_as_float(((unsigned)h) << 16);
}

// BN scale/shift from a replicated stats slot -> LDS ssS[256].
// Replica sum split across all 256 threads (S by t<128, Q by t>=128) so the
// 128 L2-resident loads per thread pipeline; one internal barrier.
__device__ inline void compute_ss_lds(const float* __restrict__ stats,
                                      const float* __restrict__ g,
                                      const float* __restrict__ be, float cnt,
                                      float* ssS, float* tmp) {
  const int tid = threadIdx.x;
  const int c = tid & 127;
  float acc = 0.f;
  if (tid < 128) {
    for (int r = 0; r < NREP; ++r) acc += stats[r * 512 + c];
  } else {
    for (int r = 0; r < NREP; ++r) acc += stats[r * 512 + 256 + c];
  }
  tmp[tid] = acc;
  __syncthreads();
  if (tid < 128) {
    const float S = tmp[tid], Q = tmp[128 + tid];
    const float m = S / cnt;
    const float v = Q / cnt - m * m;
    const float sc = g[c] * rsqrtf(v + BN_EPS);
    ssS[c] = sc;
    ssS[128 + c] = be[c] - m * sc;
  }
}

// ---------------------------------------------------------------------------
// B-resident barrier-free GEMM (bf16 A): C[N][64-slice] = op(A)@W + bias.
// ---------------------------------------------------------------------------
template <bool NORM_A, bool MASKED>
__global__ __launch_bounds__(256, 4) void gemm_bf16(
    const ushort* __restrict__ A, const ushort* __restrict__ WTh,
    const ushort* __restrict__ WTl, const float* __restrict__ bias,
    const float* __restrict__ statsIn, const float* __restrict__ gN,
    const float* __restrict__ beN, const float* __restrict__ cntPtr,
    const int* __restrict__ tmask, ushort* __restrict__ C,
    float* __restrict__ statsOut, int nrows) {
  __shared__ ushort SB[16384];  // Bh[8192] | Bl[8192]; reused: Cs[128][72]+red
  __shared__ float ssS[256];
  __shared__ float tmpS[256];
  ushort* Bh = SB;
  ushort* Bl = SB + 8192;
  const int tid = threadIdx.x;
  const int w = tid >> 6, lane = tid & 63, lr = lane & 15, lg = lane >> 4;
  const int rt = blockIdx.x >> 1, ct = blockIdx.x & 1;
  const int rowBase = rt * 128, cBase = ct * 64;
  const int rep = blockIdx.x & (NREP - 1);

  // ---- stage B once (swizzle: byte ^= (col&7)<<4 within 256B row) ----
  {
    const int cc = tid >> 2;
    const ushort* sH = WTh + (size_t)(cBase + cc) * 128;
    const ushort* sL = WTl + (size_t)(cBase + cc) * 128;
    char* BhB = (char*)Bh;
    char* BlB = (char*)Bl;
#pragma unroll
    for (int i = 0; i < 4; ++i) {
      const int slot = (tid & 3) * 4 + i;
      const int off = (cc * 256 + slot * 16) ^ ((cc & 7) << 4);
      *(short8v*)(BhB + off) = *(const short8v*)(sH + slot * 8);
      *(short8v*)(BlB + off) = *(const short8v*)(sL + slot * 8);
    }
  }
  if (NORM_A) {
    const float cnt = cntPtr ? fmaxf(cntPtr[0], 1.f) : (float)nrows;
    compute_ss_lds(statsIn, gN, beN, cnt, ssS, tmpS);
  }

  // ---- prefetch all A fragments ----
  const int row0 = rowBase + w * 32 + lr;
  const int row1 = row0 + 16;
  const bool ok0 = row0 < nrows, ok1 = row1 < nrows;
  const short8v szero = {0, 0, 0, 0, 0, 0, 0, 0};
  const ushort* aP0 = A + (size_t)row0 * 128 + lg * 8;
  const ushort* aP1 = A + (size_t)row1 * 128 + lg * 8;
  short8v ar0[4], ar1[4];
#pragma unroll
  for (int c = 0; c < 4; ++c) {
    ar0[c] = ok0 ? *(const short8v*)(aP0 + c * 32) : szero;
    ar1[c] = ok1 ? *(const short8v*)(aP1 + c * 32) : szero;
  }
  __syncthreads();

  const f32x4 fzero = {0.f, 0.f, 0.f, 0.f};
  f32x4 acc[2][4];
#pragma unroll
  for (int i = 0; i < 2; ++i)
#pragma unroll
    for (int j = 0; j < 4; ++j) acc[i][j] = fzero;

  const char* BhB = (const char*)Bh;
  const char* BlB = (const char*)Bl;
  __builtin_amdgcn_s_setprio(1);
#pragma unroll
  for (int c = 0; c < 4; ++c) {
    short8v a0 = ar0[c], a1 = ar1[c];
    if (NORM_A) {
      const int kb = c * 32 + lg * 8;
      const float4 s0 = *(const float4*)&ssS[kb];
      const float4 s1 = *(const float4*)&ssS[kb + 4];
      const float4 h0 = *(const float4*)&ssS[128 + kb];
      const float4 h1 = *(const float4*)&ssS[128 + kb + 4];
      const float sv[8] = {s0.x, s0.y, s0.z, s0.w, s1.x, s1.y, s1.z, s1.w};
      const float hv[8] = {h0.x, h0.y, h0.z, h0.w, h1.x, h1.y, h1.z, h1.w};
#pragma unroll
      for (int j = 0; j < 8; ++j) {
        a0[j] = (short)bf_hi(fmaxf(fmaf(bf_f((ushort)a0[j]), sv[j], hv[j]), 0.f));
        a1[j] = (short)bf_hi(fmaxf(fmaf(bf_f((ushort)a1[j]), sv[j], hv[j]), 0.f));
      }
    }
#pragma unroll
    for (int nf = 0; nf < 4; ++nf) {
      const int brow = nf * 16 + lr;
      const int off = (brow * 256 + (c * 4 + lg) * 16) ^ ((lr & 7) << 4);
      const short8v bh = *(const short8v*)(BhB + off);
      const short8v bl = *(const short8v*)(BlB + off);
      acc[0][nf] = __builtin_amdgcn_mfma_f32_16x16x32_bf16(a0, bh, acc[0][nf], 0, 0, 0);
      acc[1][nf] = __builtin_amdgcn_mfma_f32_16x16x32_bf16(a1, bh, acc[1][nf], 0, 0, 0);
      acc[0][nf] = __builtin_amdgcn_mfma_f32_16x16x32_bf16(a0, bl, acc[0][nf], 0, 0, 0);
      acc[1][nf] = __builtin_amdgcn_mfma_f32_16x16x32_bf16(a1, bl, acc[1][nf], 0, 0, 0);
    }
  }
  __builtin_amdgcn_s_setprio(0);

  // ---- epilogue: acc -> LDS bounce; stats partials ----
  float mrow[2][4];
#pragma unroll
  for (int mf = 0; mf < 2; ++mf)
#pragma unroll
    for (int rr = 0; rr < 4; ++rr) {
      const int row = rowBase + w * 32 + mf * 16 + lg * 4 + rr;
      float m = 0.f;
      if (row < nrows) m = MASKED ? ((tmask[row] > 0) ? 1.f : 0.f) : 1.f;
      mrow[mf][rr] = m;
    }
  __syncthreads();  // all waves done reading B
  ushort* Cs = SB;                      // [128][72]
  float* Sred = (float*)(SB + 9216);    // [4][64]
  float* Sq = Sred + 256;               // [4][64]
#pragma unroll
  for (int nf = 0; nf < 4; ++nf) {
    const int col = nf * 16 + lr;
    const float bcol = bias[cBase + col];
    float ps = 0.f, pq = 0.f;
#pragma unroll
    for (int mf = 0; mf < 2; ++mf) {
      const f32x4 vv = acc[mf][nf];
#pragma unroll
      for (int rr = 0; rr < 4; ++rr) {
        const float o = vv[rr] + bcol;
        const int rl = w * 32 + mf * 16 + lg * 4 + rr;
        Cs[rl * 72 + col] = bf_hi(o);
        const float mo = mrow[mf][rr] * o;
        ps += mo;
        pq += mo * o;
      }
    }
    ps += __shfl_xor(ps, 16);
    ps += __shfl_xor(ps, 32);
    pq += __shfl_xor(pq, 16);
    pq += __shfl_xor(pq, 32);
    if (lg == 0) {
      Sred[w * 64 + col] = ps;
      Sq[w * 64 + col] = pq;
    }
  }
  __syncthreads();
  {
    const int rl = tid >> 1, half = tid & 1;
    const int grow = rowBase + rl;
    if (grow < nrows) {
      ushort* dstp = C + (size_t)grow * 128 + cBase + half * 32;
      const ushort* srcp = Cs + rl * 72 + half * 32;
#pragma unroll
      for (int j = 0; j < 4; ++j)
        *(short8v*)(dstp + j * 8) = *(const short8v*)(srcp + j * 8);
    }
  }
  if (tid < 64) {
    float s = 0.f;
#pragma unroll
    for (int q = 0; q < 4; ++q) s += Sred[q * 64 + tid];
    atomicAdd(&statsOut[rep * 512 + cBase + tid], s);
  } else if (tid < 128) {
    float s = 0.f;
#pragma unroll
    for (int q = 0; q < 4; ++q) s += Sq[q * 64 + tid - 64];
    atomicAdd(&statsOut[rep * 512 + 256 + cBase + tid - 64], s);
  }
}

// ---------------------------------------------------------------------------
// FUSED agg+GEMM1: A fragments computed on the fly from CSR message passing.
// ---------------------------------------------------------------------------
__global__ __launch_bounds__(256, 4) void gemm_agg(
    const ushort* __restrict__ x, const ushort* __restrict__ feat,
    const int* __restrict__ offs, const int2* __restrict__ pairs,
    const float* __restrict__ deps, int layer, const ushort* __restrict__ WTh,
    const ushort* __restrict__ WTl, const float* __restrict__ bias,
    ushort* __restrict__ C, float* __restrict__ statsOut,
    int* __restrict__ tmask, int nrows) {
  __shared__ ushort SB[16384];
  ushort* Bh = SB;
  ushort* Bl = SB + 8192;
  const int tid = threadIdx.x;
  const int w = tid >> 6, lane = tid & 63, lr = lane & 15, lg = lane >> 4;
  const int rt = blockIdx.x >> 1, ct = blockIdx.x & 1;
  const int rowBase = rt * 128, cBase = ct * 64;
  const int rep = blockIdx.x & (NREP - 1);

  // ---- stage B once ----
  {
    const int cc = tid >> 2;
    const ushort* sH = WTh + (size_t)(cBase + cc) * 128;
    const ushort* sL = WTl + (size_t)(cBase + cc) * 128;
    char* BhB = (char*)Bh;
    char* BlB = (char*)Bl;
#pragma unroll
    for (int i = 0; i < 4; ++i) {
      const int slot = (tid & 3) * 4 + i;
      const int off = (cc * 256 + slot * 16) ^ ((cc & 7) << 4);
      *(short8v*)(BhB + off) = *(const short8v*)(sH + slot * 8);
      *(short8v*)(BlB + off) = *(const short8v*)(sL + slot * 8);
    }
  }

  const float ce = 1.f + deps[layer];
  const int row0 = rowBase + w * 32 + lr;
  const int row1 = row0 + 16;
  int o0a = 0, o1a = 0, o0b = 0, o1b = 0;
  if (row0 < nrows) {
    o0a = offs[layer * Nn + row0];
    o1a = offs[layer * Nn + row0 + 1];
  }
  if (row1 < nrows) {
    o0b = offs[layer * Nn + row1];
    o1b = offs[layer * Nn + row1 + 1];
  }
  if (lg == 0) {
    if (row0 < nrows) tmask[row0] = (o1a > o0a) ? 1 : 0;
    if (row1 < nrows) tmask[row1] = (o1b > o0b) ? 1 : 0;
  }

  short8v ar0[4], ar1[4];
  {
    float a[4][8];
#pragma unroll
    for (int c = 0; c < 4; ++c)
#pragma unroll
      for (int j = 0; j < 8; ++j) a[c][j] = 0.f;
    for (int p = o0a; p < o1a; ++p) {
      const int2 pr = pairs[p];
      const float wgt = __int_as_float(pr.y);
      const ushort* xr = x + (size_t)pr.x * 128 + lg * 8;
#pragma unroll
      for (int c = 0; c < 4; ++c) {
        const short8v xv = *(const short8v*)(xr + c * 32);
#pragma unroll
        for (int j = 0; j < 8; ++j)
          a[c][j] = fmaf(wgt, bf_f((ushort)xv[j]), a[c][j]);
      }
    }
    if (o1a > o0a) {
      const ushort* fr = feat + (size_t)row0 * 128 + lg * 8;
#pragma unroll
      for (int c = 0; c < 4; ++c) {
        const short8v fv = *(const short8v*)(fr + c * 32);
#pragma unroll
        for (int j = 0; j < 8; ++j)
          a[c][j] = fmaf(ce, bf_f((ushort)fv[j]), a[c][j]);
      }
    }
#pragma unroll
    for (int c = 0; c < 4; ++c)
#pragma unroll
      for (int j = 0; j < 8; ++j) ar0[c][j] = (short)bf_hi(a[c][j]);
  }
  {
    float a[4][8];
#pragma unroll
    for (int c = 0; c < 4; ++c)
#pragma unroll
      for (int j = 0; j < 8; ++j) a[c][j] = 0.f;
    for (int p = o0b; p < o1b; ++p) {
      const int2 pr = pairs[p];
      const float wgt = __int_as_float(pr.y);
      const ushort* xr = x + (size_t)pr.x * 128 + lg * 8;
#pragma unroll
      for (int c = 0; c < 4; ++c) {
        const short8v xv = *(const short8v*)(xr + c * 32);
#pragma unroll
        for (int j = 0; j < 8; ++j)
          a[c][j] = fmaf(wgt, bf_f((ushort)xv[j]), a[c][j]);
      }
    }
    if (o1b > o0b) {
      const ushort* fr = feat + (size_t)row1 * 128 + lg * 8;
#pragma unroll
      for (int c = 0; c < 4; ++c) {
        const short8v fv = *(const short8v*)(fr + c * 32);
#pragma unroll
        for (int j = 0; j < 8; ++j)
          a[c][j] = fmaf(ce, bf_f((ushort)fv[j]), a[c][j]);
      }
    }
#pragma unroll
    for (int c = 0; c < 4; ++c)
#pragma unroll
      for (int j = 0; j < 8; ++j) ar1[c][j] = (short)bf_hi(a[c][j]);
  }
  __syncthreads();

  const f32x4 fzero = {0.f, 0.f, 0.f, 0.f};
  f32x4 acc[2][4];
#pragma unroll
  for (int i = 0; i < 2; ++i)
#pragma unroll
    for (int j = 0; j < 4; ++j) acc[i][j] = fzero;

  const char* BhB = (const char*)Bh;
  const char* BlB = (const char*)Bl;
  __builtin_amdgcn_s_setprio(1);
#pragma unroll
  for (int c = 0; c < 4; ++c) {
    const short8v a0 = ar0[c], a1 = ar1[c];
#pragma unroll
    for (int nf = 0; nf < 4; ++nf) {
      const int brow = nf * 16 + lr;
      const int off = (brow * 256 + (c * 4 + lg) * 16) ^ ((lr & 7) << 4);
      const short8v bh = *(const short8v*)(BhB + off);
      const short8v bl = *(const short8v*)(BlB + off);
      acc[0][nf] = __builtin_amdgcn_mfma_f32_16x16x32_bf16(a0, bh, acc[0][nf], 0, 0, 0);
      acc[1][nf] = __builtin_amdgcn_mfma_f32_16x16x32_bf16(a1, bh, acc[1][nf], 0, 0, 0);
      acc[0][nf] = __builtin_amdgcn_mfma_f32_16x16x32_bf16(a0, bl, acc[0][nf], 0, 0, 0);
      acc[1][nf] = __builtin_amdgcn_mfma_f32_16x16x32_bf16(a1, bl, acc[1][nf], 0, 0, 0);
    }
  }
  __builtin_amdgcn_s_setprio(0);

  // ---- epilogue: mask via shfl of per-row deg flags ----
  const float dga = (o1a > o0a) ? 1.f : 0.f;
  const float dgb = (o1b > o0b) ? 1.f : 0.f;
  float mrow[2][4];
#pragma unroll
  for (int rr = 0; rr < 4; ++rr) {
    const int srcl = lg * 4 + rr;  // lane (lg=0 group) holding that row's deg
    mrow[0][rr] = __shfl(dga, srcl, 64);
    mrow[1][rr] = __shfl(dgb, srcl, 64);
  }
#pragma unroll
  for (int mf = 0; mf < 2; ++mf)
#pragma unroll
    for (int rr = 0; rr < 4; ++rr) {
      const int row = rowBase + w * 32 + mf * 16 + lg * 4 + rr;
      if (row >= nrows) mrow[mf][rr] = 0.f;
    }
  __syncthreads();
  ushort* Cs = SB;                    // [128][72]
  float* Sred = (float*)(SB + 9216);  // [4][64]
  float* Sq = Sred + 256;
#pragma unroll
  for (int nf = 0; nf < 4; ++nf) {
    const int col = nf * 16 + lr;
    const float bcol = bias[cBase + col];
    float ps = 0.f, pq = 0.f;
#pragma unroll
    for (int mf = 0; mf < 2; ++mf) {
      const f32x4 vv = acc[mf][nf];
#pragma unroll
      for (int rr = 0; rr < 4; ++rr) {
        const float o = vv[rr] + bcol;
        const int rl = w * 32 + mf * 16 + lg * 4 + rr;
        Cs[rl * 72 + col] = bf_hi(o);
        const float mo = mrow[mf][rr] * o;
        ps += mo;
        pq += mo * o;
      }
    }
    ps += __shfl_xor(ps, 16);
    ps += __shfl_xor(ps, 32);
    pq += __shfl_xor(pq, 16);
    pq += __shfl_xor(pq, 32);
    if (lg == 0) {
      Sred[w * 64 + col] = ps;
      Sq[w * 64 + col] = pq;
    }
  }
  __syncthreads();
  {
    const int rl = tid >> 1, half = tid & 1;
    const int grow = rowBase + rl;
    if (grow < nrows) {
      ushort* dstp = C + (size_t)grow * 128 + cBase + half * 32;
      const ushort* srcp = Cs + rl * 72 + half * 32;
#pragma unroll
      for (int j = 0; j < 4; ++j)
        *(short8v*)(dstp + j * 8) = *(const short8v*)(srcp + j * 8);
    }
  }
  if (tid < 64) {
    float s = 0.f;
#pragma unroll
    for (int q = 0; q < 4; ++q) s += Sred[q * 64 + tid];
    atomicAdd(&statsOut[rep * 512 + cBase + tid], s);
  } else if (tid < 128) {
    float s = 0.f;
#pragma unroll
    for (int q = 0; q < 4; ++q) s += Sq[q * 64 + tid - 64];
    atomicAdd(&statsOut[rep * 512 + 256 + cBase + tid - 64], s);
  }
}

// ---------------------------------------------------------------------------
// GEMM #1: fp32 A (dag_x), K=64, hi/lo-split A (3 MFMAs). Same epilogue.
// ---------------------------------------------------------------------------
__global__ __launch_bounds__(256, 4) void gemm_f32a(
    const float* __restrict__ A, const ushort* __restrict__ WTh,
    const ushort* __restrict__ WTl, const float* __restrict__ bias,
    ushort* __restrict__ C, float* __restrict__ statsOut, int nrows) {
  __shared__ ushort SB[11264];  // Bh[4096] | Bl[4096]; reused Cs[128][72]+red
  ushort* Bh = SB;
  ushort* Bl = SB + 4096;
  const int tid = threadIdx.x;
  const int w = tid >> 6, lane = tid & 63, lr = lane & 15, lg = lane >> 4;
  const int rt = blockIdx.x >> 1, ct = blockIdx.x & 1;
  const int rowBase = rt * 128, cBase = ct * 64;
  const int rep = blockIdx.x & (NREP - 1);

  {
    const int cc = tid >> 2;
    const ushort* sH = WTh + (size_t)(cBase + cc) * 64;
    const ushort* sL = WTl + (size_t)(cBase + cc) * 64;
    char* BhB = (char*)Bh;
    char* BlB = (char*)Bl;
#pragma unroll
    for (int i = 0; i < 2; ++i) {
      const int slot = (tid & 3) * 2 + i;
      const int off = (cc * 128 + slot * 16) ^ ((cc & 7) << 4);
      *(short8v*)(BhB + off) = *(const short8v*)(sH + slot * 8);
      *(short8v*)(BlB + off) = *(const short8v*)(sL + slot * 8);
    }
  }

  const int row0 = rowBase + w * 32 + lr;
  const int row1 = row0 + 16;
  const bool ok0 = row0 < nrows, ok1 = row1 < nrows;
  const float4 fz4 = make_float4(0.f, 0.f, 0.f, 0.f);
  const float* aP0 = A + (size_t)row0 * 64 + lg * 8;
  const float* aP1 = A + (size_t)row1 * 64 + lg * 8;
  float4 ar0[2][2], ar1[2][2];
#pragma unroll
  for (int c = 0; c < 2; ++c) {
    ar0[c][0] = ok0 ? *(const float4*)(aP0 + c * 32) : fz4;
    ar0[c][1] = ok0 ? *(const float4*)(aP0 + c * 32 + 4) : fz4;
    ar1[c][0] = ok1 ? *(const float4*)(aP1 + c * 32) : fz4;
    ar1[c][1] = ok1 ? *(const float4*)(aP1 + c * 32 + 4) : fz4;
  }
  __syncthreads();

  const f32x4 fzero = {0.f, 0.f, 0.f, 0.f};
  f32x4 acc[2][4];
#pragma unroll
  for (int i = 0; i < 2; ++i)
#pragma unroll
    for (int j = 0; j < 4; ++j) acc[i][j] = fzero;

  const char* BhB = (const char*)Bh;
  const char* BlB = (const char*)Bl;
  __builtin_amdgcn_s_setprio(1);
#pragma unroll
  for (int c = 0; c < 2; ++c) {
    const float v0[8] = {ar0[c][0].x, ar0[c][0].y, ar0[c][0].z, ar0[c][0].w,
                         ar0[c][1].x, ar0[c][1].y, ar0[c][1].z, ar0[c][1].w};
    const float v1[8] = {ar1[c][0].x, ar1[c][0].y, ar1[c][0].z, ar1[c][0].w,
                         ar1[c][1].x, ar1[c][1].y, ar1[c][1].z, ar1[c][1].w};
    short8v a0h, a0l, a1h, a1l;
#pragma unroll
    for (int j = 0; j < 8; ++j) {
      ushort hh = bf_hi(v0[j]);
      a0h[j] = (short)hh;
      a0l[j] = (short)bf_hi(v0[j] - bf_f(hh));
      hh = bf_hi(v1[j]);
      a1h[j] = (short)hh;
      a1l[j] = (short)bf_hi(v1[j] - bf_f(hh));
    }
#pragma unroll
    for (int nf = 0; nf < 4; ++nf) {
      const int brow = nf * 16 + lr;
      const int off = (brow * 128 + (c * 4 + lg) * 16) ^ ((lr & 7) << 4);
      const short8v bh = *(const short8v*)(BhB + off);
      const short8v bl = *(const short8v*)(BlB + off);
      acc[0][nf] = __builtin_amdgcn_mfma_f32_16x16x32_bf16(a0h, bh, acc[0][nf], 0, 0, 0);
      acc[1][nf] = __builtin_amdgcn_mfma_f32_16x16x32_bf16(a1h, bh, acc[1][nf], 0, 0, 0);
      acc[0][nf] = __builtin_amdgcn_mfma_f32_16x16x32_bf16(a0l, bh, acc[0][nf], 0, 0, 0);
      acc[1][nf] = __builtin_amdgcn_mfma_f32_16x16x32_bf16(a1l, bh, acc[1][nf], 0, 0, 0);
      acc[0][nf] = __builtin_amdgcn_mfma_f32_16x16x32_bf16(a0h, bl, acc[0][nf], 0, 0, 0);
      acc[1][nf] = __builtin_amdgcn_mfma_f32_16x16x32_bf16(a1h, bl, acc[1][nf], 0, 0, 0);
    }
  }
  __builtin_amdgcn_s_setprio(0);

  __syncthreads();
  ushort* Cs = SB;                    // [128][72]
  float* Sred = (float*)(SB + 9216);  // [4][64]
  float* Sq = Sred + 256;
#pragma unroll
  for (int nf = 0; nf < 4; ++nf) {
    const int col = nf * 16 + lr;
    const float bcol = bias[cBase + col];
    float ps = 0.f, pq = 0.f;
#pragma unroll
    for (int mf = 0; mf < 2; ++mf) {
      const f32x4 vv = acc[mf][nf];
#pragma unroll
      for (int rr = 0; rr < 4; ++rr) {
        const float o = vv[rr] + bcol;
        const int rl = w * 32 + mf * 16 + lg * 4 + rr;
        Cs[rl * 72 + col] = bf_hi(o);
        const int row = rowBase + rl;
        const float m = (row < nrows) ? 1.f : 0.f;
        const float mo = m * o;
        ps += mo;
        pq += mo * o;
      }
    }
    ps += __shfl_xor(ps, 16);
    ps += __shfl_xor(ps, 32);
    pq += __shfl_xor(pq, 16);
    pq += __shfl_xor(pq, 32);
    if (lg == 0) {
      Sred[w * 64 + col] = ps;
      Sq[w * 64 + col] = pq;
    }
  }
  __syncthreads();
  {
    const int rl = tid >> 1, half = tid & 1;
    const int grow = rowBase + rl;
    if (grow < nrows) {
      ushort* dstp = C + (size_t)grow * 128 + cBase + half * 32;
      const ushort* srcp = Cs + rl * 72 + half * 32;
#pragma unroll
      for (int j = 0; j < 4; ++j)
        *(short8v*)(dstp + j * 8) = *(const short8v*)(srcp + j * 8);
    }
  }
  if (tid < 64) {
    float s = 0.f;
#pragma unroll
    for (int q = 0; q < 4; ++q) s += Sred[q * 64 + tid];
    atomicAdd(&statsOut[rep * 512 + cBase + tid], s);
  } else if (tid < 128) {
    float s = 0.f;
#pragma unroll
    for (int q = 0; q < 4; ++q) s += Sq[q * 64 + tid - 64];
    atomicAdd(&statsOut[rep * 512 + 256 + cBase + tid - 64], s);
  }
}

// Weight transpose + hi/lo split: 8 slots of 32768 ushorts (hi, lo@+16384)
__global__ __launch_bounds__(256) void wsplit_kernel(
    const float* __restrict__ W1, const float* __restrict__ W2,
    const float* __restrict__ dW1, const float* __restrict__ dW2,
    ushort* __restrict__ wsT) {
  const int t = blockIdx.x * 256 + threadIdx.x;
  const int slot = t >> 14;
  const int idx = t & 16383;
  if (slot >= 8) return;
  const int Ks = (slot == 0) ? 64 : 128;
  if (idx >= 128 * Ks) return;
  const int c = idx / Ks;
  const int k = idx - c * Ks;
  float v;
  if (slot == 0) v = W1[k * 128 + c];
  else if (slot == 1) v = W2[k * 128 + c];
  else if (slot < 5) v = dW1[(slot - 2) * 16384 + k * 128 + c];
  else v = dW2[(slot - 5) * 16384 + k * 128 + c];
  const ushort h = bf_hi(v);
  const ushort l = bf_hi(v - bf_f(h));
  wsT[slot * 32768 + c * Ks + k] = h;
  wsT[slot * 32768 + 16384 + c * Ks + k] = l;
}

// feat = relu(y*sc+sh); also zeroes x (replaces the xbuf memset dispatch).
__global__ __launch_bounds__(256) void normrelu_kernel(
    const ushort* __restrict__ in, const float* __restrict__ stats,
    const float* __restrict__ g, const float* __restrict__ be, float cntFixed,
    ushort* __restrict__ outp, ushort* __restrict__ xz) {
  __shared__ float ssS[256];
  __shared__ float tmpS[256];
  compute_ss_lds(stats, g, be, cntFixed, ssS, tmpS);
  __syncthreads();
  const int tid = threadIdx.x;
  const int c4 = (tid & 31) * 4;
  const float4 sc = *(const float4*)&ssS[c4];
  const float4 sh = *(const float4*)&ssS[128 + c4];
  const int rowBase = blockIdx.x * 64;
  const ushort4 z4 = make_ushort4(0, 0, 0, 0);
#pragma unroll
  for (int it = 0; it < 8; ++it) {
    const int row = rowBase + it * 8 + (tid >> 5);
    if (row >= Nn) continue;
    const size_t idx = (size_t)row * 32 + (tid & 31);
    const ushort4 v = ((const ushort4*)in)[idx];
    ushort4 o;
    o.x = bf_hi(fmaxf(fmaf(bf_f(v.x), sc.x, sh.x), 0.f));
    o.y = bf_hi(fmaxf(fmaf(bf_f(v.y), sc.y, sh.y), 0.f));
    o.z = bf_hi(fmaxf(fmaf(bf_f(v.z), sc.z, sh.z), 0.f));
    o.w = bf_hi(fmaxf(fmaf(bf_f(v.w), sc.w, sh.w), 0.f));
    ((ushort4*)outp)[idx] = o;
    ((ushort4*)xz)[idx] = z4;
  }
}

// x += (tmask>0) * relu(y*sc+sh)
__global__ __launch_bounds__(256) void normrelu_acc_kernel(
    const ushort* __restrict__ in, const float* __restrict__ stats,
    const float* __restrict__ g, const float* __restrict__ be,
    const float* __restrict__ cntPtr, const int* __restrict__ tmask,
    ushort* __restrict__ x) {
  __shared__ float ssS[256];
  __shared__ float tmpS[256];
  compute_ss_lds(stats, g, be, fmaxf(cntPtr[0], 1.f), ssS, tmpS);
  __syncthreads();
  const int tid = threadIdx.x;
  const int c4 = (tid & 31) * 4;
  const float4 sc = *(const float4*)&ssS[c4];
  const float4 sh = *(const float4*)&ssS[128 + c4];
  const int rowBase = blockIdx.x * 64;
#pragma unroll
  for (int it = 0; it < 8; ++it) {
    const int row = rowBase + it * 8 + (tid >> 5);
    if (row >= Nn || tmask[row] <= 0) continue;
    const size_t idx = (size_t)row * 32 + (tid & 31);
    const ushort4 v = ((const ushort4*)in)[idx];
    ushort4 xo = ((const ushort4*)x)[idx];
    xo.x = bf_hi(bf_f(xo.x) + fmaxf(fmaf(bf_f(v.x), sc.x, sh.x), 0.f));
    xo.y = bf_hi(bf_f(xo.y) + fmaxf(fmaf(bf_f(v.y), sc.y, sh.y), 0.f));
    xo.z = bf_hi(bf_f(xo.z) + fmaxf(fmaf(bf_f(v.z), sc.z, sh.z), 0.f));
    xo.w = bf_hi(bf_f(xo.w) + fmaxf(fmaf(bf_f(v.w), sc.w, sh.w), 0.f));
    ((ushort4*)x)[idx] = xo;
  }
}

__global__ __launch_bounds__(256) void scatter_leaves_kernel(
    const int* __restrict__ leaves, const ushort* __restrict__ feat,
    ushort* __restrict__ x, int nl) {
  const int gid = blockIdx.x * 256 + threadIdx.x;
  const int j = gid >> 5;
  if (j >= nl) return;
  const int node = leaves[j];
  const int c4 = (gid & 31) * 4;
  *(ushort4*)&x[(size_t)node * 128 + c4] =
      *(const ushort4*)&feat[(size_t)node * 128 + c4];
}

// ---------------- CSR build ----------------
__global__ __launch_bounds__(256) void deg_count_kernel(
    const int* __restrict__ dst, const int* __restrict__ lmask,
    int* __restrict__ cnts) {
  const int e = blockIdx.x * 256 + threadIdx.x;
  if (e >= Ee) return;
  atomicAdd(&cnts[lmask[e] * Nn + dst[e]], 1);
}

// scan1 + fused per-layer target count (nodes with deg>0) -> tcountf[0..2]
__global__ __launch_bounds__(256) void scan1_kernel(const int* __restrict__ in,
                                                    int* __restrict__ out,
                                                    int* __restrict__ bsum,
                                                    float* __restrict__ tcountf,
                                                    int n) {
  __shared__ int lds[256];
  __shared__ float tcS[3];
  const int tid = threadIdx.x;
  const int base = blockIdx.x * 2048 + tid * 8;
  int vals[8];
  int tsum = 0;
  float t0 = 0.f, t1 = 0.f, t2 = 0.f;
#pragma unroll
  for (int j = 0; j < 8; ++j) {
    const int i = base + j;
    const int v = (i < n) ? in[i] : 0;
    if (v > 0) {
      if (i < Nn) t0 += 1.f;
      else if (i < 2 * Nn) t1 += 1.f;
      else t2 += 1.f;
    }
    vals[j] = tsum;
    tsum += v;
  }
  lds[tid] = tsum;
  if (tid < 3) tcS[tid] = 0.f;
  __syncthreads();
  if (t0 != 0.f) atomicAdd(&tcS[0], t0);
  if (t1 != 0.f) atomicAdd(&tcS[1], t1);
  if (t2 != 0.f) atomicAdd(&tcS[2], t2);
  for (int off = 1; off < 256; off <<= 1) {
    const int y = (tid >= off) ? lds[tid - off] : 0;
    __syncthreads();
    lds[tid] += y;
    __syncthreads();
  }
  const int texcl = (tid > 0) ? lds[tid - 1] : 0;
#pragma unroll
  for (int j = 0; j < 8; ++j)
    if (base + j < n) out[base + j] = texcl + vals[j];
  if (tid == 255) bsum[blockIdx.x] = lds[255];
  __syncthreads();
  if (tid < 3 && tcS[tid] != 0.f) atomicAdd(&tcountf[tid], tcS[tid]);
}

// scan3 with scan2 fused: each block redundantly scans the 147 block sums.
__global__ __launch_bounds__(256) void scan3_kernel(int* __restrict__ out,
                                                    int* __restrict__ cursor,
                                                    const int* __restrict__ bsum,
                                                    int nb, int n, int etot) {
  __shared__ int bs[256];
  const int tid = threadIdx.x;
  const int v = (tid < nb) ? bsum[tid] : 0;
  bs[tid] = v;
  __syncthreads();
  for (int off = 1; off < 256; off <<= 1) {
    const int y = (tid >= off) ? bs[tid - off] : 0;
    __syncthreads();
    bs[tid] += y;
    __syncthreads();
  }
  const int i = blockIdx.x * 256 + tid;
  if (i >= n) return;
  const int b = i >> 11;
  const int excl = (b > 0) ? bs[b - 1] : 0;
  const int val = out[i] + excl;
  out[i] = val;
  cursor[i] = val;
  if (i == n - 1) out[n] = etot;
}

__global__ __launch_bounds__(256) void csr_fill_kernel(
    const int* __restrict__ src, const int* __restrict__ dst,
    const float* __restrict__ mult, const int* __restrict__ lmask,
    int* __restrict__ cursor, int2* __restrict__ pairs) {
  const int e = blockIdx.x * 256 + threadIdx.x;
  if (e >= Ee) return;
  const int slot = atomicAdd(&cursor[lmask[e] * Nn + dst[e]], 1);
  pairs[slot] = make_int2(src[e], __float_as_int(mult[e]));
}

// ---------------- readout: replicated-bucket counting-sort pool -----------
__global__ __launch_bounds__(256) void phist_kernel(const int* __restrict__ ridx,
                                                    const int* __restrict__ batch,
                                                    int* __restrict__ cnt, int n) {
  const int i = blockIdx.x * 256 + threadIdx.x;
  if (i >= n) return;
  atomicAdd(&cnt[batch[ridx[i]] * PR + (i & (PR - 1))], 1);
}

// exclusive scan over 256*PR = 8192 buckets (single block, 32 elems/thread)
__global__ void pscan_kernel(int* __restrict__ cnt, int* __restrict__ cur) {
  __shared__ int l[256];
  const int t = threadIdx.x;
  const int base = t * 32;
  int vals[32];
  int tsum = 0;
#pragma unroll
  for (int j = 0; j < 32; ++j) {
    const int v = cnt[base + j];
    vals[j] = tsum;
    tsum += v;
  }
  l[t] = tsum;
  __syncthreads();
  for (int off = 1; off < 256; off <<= 1) {
    const int y = (t >= off) ? l[t - off] : 0;
    __syncthreads();
    l[t] += y;
    __syncthreads();
  }
  const int excl = (t > 0) ? l[t - 1] : 0;
#pragma unroll
  for (int j = 0; j < 32; ++j) {
    const int v = excl + vals[j];
    cnt[base + j] = v;
    cur[base + j] = v;
  }
}

__global__ __launch_bounds__(256) void pfill_kernel(const int* __restrict__ ridx,
                                                    const int* __restrict__ batch,
                                                    int* __restrict__ cur,
                                                    int* __restrict__ sorted,
                                                    int n) {
  const int i = blockIdx.x * 256 + threadIdx.x;
  if (i >= n) return;
  const int node = ridx[i];
  const int slot = atomicAdd(&cur[batch[node] * PR + (i & (PR - 1))], 1);
  sorted[slot] = node;
}

// Parallel pool: 8 slices per graph -> Ppart[g*8+slice][128] (no atomics)
__global__ __launch_bounds__(256) void ppool_kernel(const int* __restrict__ sorted,
                                                    const int* __restrict__ offs,
                                                    const ushort* __restrict__ x,
                                                    float* __restrict__ Ppart,
                                                    int n) {
  __shared__ float part[4][256];
  const int bid = blockIdx.x;
  const int g = bid >> 3, slice = bid & (PSL - 1);
  const int w = threadIdx.x >> 6;
  const int lane = threadIdx.x & 63;
  const int o0 = offs[g * PR];
  const int o1 = (g < Gg - 1) ? offs[(g + 1) * PR] : n;
  float ax = 0.f, ay = 0.f;
  for (int p = o0 + slice * 4 + w; p < o1; p += 32) {
    const int node = sorted[p];
    const ushort2 xv = *(const ushort2*)&x[(size_t)node * 128 + lane * 2];
    ax += bf_f(xv.x);
    ay += bf_f(xv.y);
  }
  part[w][lane * 2] = ax;
  part[w][lane * 2 + 1] = ay;
  __syncthreads();
  if (threadIdx.x < 128) {
    const int c = threadIdx.x;
    Ppart[(size_t)bid * 128 + c] =
        part[0][c] + part[1][c] + part[2][c] + part[3][c];
  }
}

// Fused preduce + final linear: out[g][t] = 0.25*sum_slices(Ppart)@Wl + bl
__global__ __launch_bounds__(128) void pout_kernel(
    const float* __restrict__ Ppart, const float* __restrict__ Wl,
    const float* __restrict__ bl, float* __restrict__ out) {
  __shared__ float Pl[128];
  const int g = blockIdx.x;
  const int t = threadIdx.x;  // 128
  float s = 0.f;
#pragma unroll
  for (int r = 0; r < PSL; ++r) s += Ppart[(size_t)(g * PSL + r) * 128 + t];
  Pl[t] = s * 0.25f;
  __syncthreads();
  if (t < Tt) {
    float acc = 0.f;
    for (int c = 0; c < 128; ++c) acc += Pl[c] * Wl[c * Tt + t];
    out[g * Tt + t] = acc + bl[t];
  }
}

extern "C" void kernel_launch(void* const* d_in, const int* in_sizes, int n_in,
                              void* d_out, int out_size, void* d_ws,
                              size_t ws_size, hipStream_t stream) {
  const float* dag_x = (const float*)d_in[0];
  const int* eidx = (const int*)d_in[1];
  const int* src = eidx;
  const int* dst = eidx + Ee;
  const float* mult = (const float*)d_in[2];
  const int* lmask = (const int*)d_in[3];
  const int* batch = (const int*)d_in[4];
  const int* leaves = (const int*)d_in[5];
  const int* readouts = (const int*)d_in[6];
  const float* W1 = (const float*)d_in[7];
  const float* b1 = (const float*)d_in[8];
  const float* g1 = (const float*)d_in[9];
  const float* be1 = (const float*)d_in[10];
  const float* W2 = (const float*)d_in[11];
  const float* b2 = (const float*)d_in[12];
  const float* g2 = (const float*)d_in[13];
  const float* be2 = (const float*)d_in[14];
  const float* dW1 = (const float*)d_in[15];
  const float* db1 = (const float*)d_in[16];
  const float* dg1 = (const float*)d_in[17];
  const float* dbe1 = (const float*)d_in[18];
  const float* dW2 = (const float*)d_in[19];
  const float* db2 = (const float*)d_in[20];
  const float* dg2 = (const float*)d_in[21];
  const float* dbe2 = (const float*)d_in[22];
  const float* deps = (const float*)d_in[23];
  const float* Wl = (const float*)d_in[24];
  const float* bl = (const float*)d_in[25];
  float* out = (float*)d_out;

  const size_t ND = (size_t)Nn * Dd;
  ushort* feat = (ushort*)d_ws;           // ND bf16
  ushort* xbuf = feat + ND;               // ND bf16
  ushort* Abuf = xbuf + ND;               // ND bf16
  ushort* Bbuf = Abuf + ND;               // ND bf16 (gemm ping-pong)
  float* statsAll = (float*)(Bbuf + ND);  // 8 slots x [128][512] = 2MB
  float* tcountf = statsAll + 8 * 65536;  // 8 (4 used) -- adjacent for memset
  int* tmask = (int*)(tcountf + 8);       // N
  ushort* wsT = (ushort*)(tmask + Nn);    // 262144 (8 weight slots, hi+lo)
  int* offs = (int*)(wsT + 262144);       // 3N+4
  int2* pairs = (int2*)(offs + 3 * Nn + 4);  // E pairs (src, mult)

  // transient overlays (xbuf region before it's initialized):
  int* cnts = (int*)xbuf;                 // 3N
  int* cursor = cnts + 3 * Nn;            // 3N
  int* bsum = cursor + 3 * Nn;            // 147
  const int nridx = in_sizes[6];          // 80000
  const int nleaves = in_sizes[5];        // 50000
  // pool overlays (Abuf dead by readout):
  int* pcnt = (int*)Abuf;                 // 256*PR (becomes offsets)
  int* pcur = pcnt + Gg * PR;             // 256*PR
  int* sorted = pcur + Gg * PR;           // nridx
  float* Ppart = (float*)(sorted + nridx);  // 2048*128

  dim3 blk(256);
  hipMemsetAsync(statsAll, 0, (8 * 65536 + 8) * sizeof(float), stream);
  wsplit_kernel<<<512, blk, 0, stream>>>(W1, W2, dW1, dW2, wsT);

  // ---- CSR build (tcount fused into scan1; scan2 fused into scan3) ----
  hipMemsetAsync(cnts, 0, 3 * Nn * sizeof(int), stream);
  deg_count_kernel<<<2344, blk, 0, stream>>>(dst, lmask, cnts);
  scan1_kernel<<<147, blk, 0, stream>>>(cnts, offs, bsum, tcountf, 3 * Nn);
  scan3_kernel<<<1172, blk, 0, stream>>>(offs, cursor, bsum, 147, 3 * Nn, Ee);
  csr_fill_kernel<<<2344, blk, 0, stream>>>(src, dst, mult, lmask, cursor, pairs);

  const int gGemm = 782 * 2;
  // ---- node feature transform ----
  gemm_f32a<<<gGemm, blk, 0, stream>>>(dag_x, wsT, wsT + 16384, b1, Abuf,
                                       statsAll + 0 * 65536, Nn);
  gemm_bf16<true, false><<<gGemm, blk, 0, stream>>>(
      Abuf, wsT + 32768, wsT + 32768 + 16384, b2, statsAll + 0 * 65536, g1,
      be1, nullptr, nullptr, Bbuf, statsAll + 1 * 65536, Nn);
  // feat = relu(bn(y2)); also zeroes xbuf (no memset dispatch)
  normrelu_kernel<<<1563, blk, 0, stream>>>(Bbuf, statsAll + 1 * 65536, g2,
                                            be2, (float)Nn, feat, xbuf);
  scatter_leaves_kernel<<<6250, blk, 0, stream>>>(leaves, feat, xbuf, nleaves);

  // ---- DAG layers (agg fused into gemm1) ----
  for (int layer = 0; layer < Ll; ++layer) {
    const int so1 = (2 + layer) * 32768;
    const int so2 = (5 + layer) * 32768;
    const int po = layer * Dd;
    float* st1 = statsAll + (size_t)(2 + 2 * layer) * 65536;
    float* st2 = statsAll + (size_t)(3 + 2 * layer) * 65536;
    gemm_agg<<<gGemm, blk, 0, stream>>>(xbuf, feat, offs, pairs, deps, layer,
                                        wsT + so1, wsT + so1 + 16384, db1 + po,
                                        Bbuf, st1, tmask, Nn);
    gemm_bf16<true, true><<<gGemm, blk, 0, stream>>>(
        Bbuf, wsT + so2, wsT + so2 + 16384, db2 + po, st1, dg1 + po, dbe1 + po,
        tcountf + layer, tmask, Abuf, st2, Nn);
    normrelu_acc_kernel<<<1563, blk, 0, stream>>>(
        Abuf, st2, dg2 + po, dbe2 + po, tcountf + layer, tmask, xbuf);
  }

  // ---- readout (replicated-bucket counting sort, no float atomics) ----
  hipMemsetAsync(pcnt, 0, Gg * PR * sizeof(int), stream);
  const int gIdx = (nridx + 255) / 256;
  phist_kernel<<<gIdx, blk, 0, stream>>>(readouts, batch, pcnt, nridx);
  pscan_kernel<<<1, blk, 0, stream>>>(pcnt, pcur);
  pfill_kernel<<<gIdx, blk, 0, stream>>>(readouts, batch, pcur, sorted, nridx);
  ppool_kernel<<<Gg * PSL, blk, 0, stream>>>(sorted, pcnt, xbuf, Ppart, nridx);
  pout_kernel<<<Gg, dim3(128), 0, stream>>>(Ppart, Wl, bl, out);
}

// Round 12
// 461.271 us; speedup vs baseline: 1.1284x; 1.1284x over previous
//
#include <hip/hip_runtime.h>

constexpr int Nn = 100000;   // nodes
constexpr int Ee = 600000;   // edges
constexpr int Dd = 128;      // hidden dim
constexpr int Ll = 3;        // DAG layers
constexpr int Gg = 256;      // graphs
constexpr int Tt = 10;       // outputs per graph
constexpr float BN_EPS = 1e-5f;
constexpr int NREP = 16;     // stats replicas (slot = [16][512] floats)
constexpr int PSL = 8;       // pool slices per graph
constexpr int PR = 32;       // counting-sort bucket replicas per graph

typedef __attribute__((ext_vector_type(8))) short short8v;
typedef __attribute__((ext_vector_type(4))) float f32x4;

__device__ inline ushort bf_hi(float f) {
  unsigned u = __float_as_uint(f);
  unsigned r = (u + 0x7FFFu + ((u >> 16) & 1u)) >> 16;
  return (ushort)r;
}
__device__ inline float bf_f(ushort h) {
  return __uint_as_float(((unsigned)h) << 16);
}

// BN scale/shift from a replicated stats slot -> LDS ssS[256] (threads 0..127)
__device__ inline void compute_ss_lds(const float* __restrict__ stats,
                                      const float* __restrict__ g,
                                      const float* __restrict__ be, float cnt,
                                      float* ssS) {
  const int c = threadIdx.x;
  if (c < 128) {
    float S = 0.f, Q = 0.f;
#pragma unroll
    for (int r = 0; r < NREP; ++r) {
      S += stats[r * 512 + c];
      Q += stats[r * 512 + 256 + c];
    }
    const float m = S / cnt;
    const float v = Q / cnt - m * m;
    const float sc = g[c] * rsqrtf(v + BN_EPS);
    ssS[c] = sc;
    ssS[128 + c] = be[c] - m * sc;
  }
}

// ---------------------------------------------------------------------------
// B-resident barrier-free GEMM (bf16 A): C[N][64-slice] = op(A)@W + bias.
// ---------------------------------------------------------------------------
template <bool NORM_A, bool MASKED>
__global__ __launch_bounds__(256, 4) void gemm_bf16(
    const ushort* __restrict__ A, const ushort* __restrict__ WTh,
    const ushort* __restrict__ WTl, const float* __restrict__ bias,
    const float* __restrict__ statsIn, const float* __restrict__ gN,
    const float* __restrict__ beN, const float* __restrict__ cntPtr,
    const int* __restrict__ tmask, ushort* __restrict__ C,
    float* __restrict__ statsOut, int nrows) {
  __shared__ ushort SB[16384];  // Bh[8192] | Bl[8192]; reused: Cs[128][72]+red
  __shared__ float ssS[256];
  ushort* Bh = SB;
  ushort* Bl = SB + 8192;
  const int tid = threadIdx.x;
  const int w = tid >> 6, lane = tid & 63, lr = lane & 15, lg = lane >> 4;
  const int rt = blockIdx.x >> 1, ct = blockIdx.x & 1;
  const int rowBase = rt * 128, cBase = ct * 64;
  const int rep = blockIdx.x & (NREP - 1);

  // ---- stage B once (swizzle: byte ^= (col&7)<<4 within 256B row) ----
  {
    const int cc = tid >> 2;
    const ushort* sH = WTh + (size_t)(cBase + cc) * 128;
    const ushort* sL = WTl + (size_t)(cBase + cc) * 128;
    char* BhB = (char*)Bh;
    char* BlB = (char*)Bl;
#pragma unroll
    for (int i = 0; i < 4; ++i) {
      const int slot = (tid & 3) * 4 + i;
      const int off = (cc * 256 + slot * 16) ^ ((cc & 7) << 4);
      *(short8v*)(BhB + off) = *(const short8v*)(sH + slot * 8);
      *(short8v*)(BlB + off) = *(const short8v*)(sL + slot * 8);
    }
  }
  if (NORM_A) {
    const float cnt = cntPtr ? fmaxf(cntPtr[0], 1.f) : (float)nrows;
    compute_ss_lds(statsIn, gN, beN, cnt, ssS);
  }

  // ---- prefetch all A fragments ----
  const int row0 = rowBase + w * 32 + lr;
  const int row1 = row0 + 16;
  const bool ok0 = row0 < nrows, ok1 = row1 < nrows;
  const short8v szero = {0, 0, 0, 0, 0, 0, 0, 0};
  const ushort* aP0 = A + (size_t)row0 * 128 + lg * 8;
  const ushort* aP1 = A + (size_t)row1 * 128 + lg * 8;
  short8v ar0[4], ar1[4];
#pragma unroll
  for (int c = 0; c < 4; ++c) {
    ar0[c] = ok0 ? *(const short8v*)(aP0 + c * 32) : szero;
    ar1[c] = ok1 ? *(const short8v*)(aP1 + c * 32) : szero;
  }
  __syncthreads();

  const f32x4 fzero = {0.f, 0.f, 0.f, 0.f};
  f32x4 acc[2][4];
#pragma unroll
  for (int i = 0; i < 2; ++i)
#pragma unroll
    for (int j = 0; j < 4; ++j) acc[i][j] = fzero;

  const char* BhB = (const char*)Bh;
  const char* BlB = (const char*)Bl;
  __builtin_amdgcn_s_setprio(1);
#pragma unroll
  for (int c = 0; c < 4; ++c) {
    short8v a0 = ar0[c], a1 = ar1[c];
    if (NORM_A) {
      const int kb = c * 32 + lg * 8;
      const float4 s0 = *(const float4*)&ssS[kb];
      const float4 s1 = *(const float4*)&ssS[kb + 4];
      const float4 h0 = *(const float4*)&ssS[128 + kb];
      const float4 h1 = *(const float4*)&ssS[128 + kb + 4];
      const float sv[8] = {s0.x, s0.y, s0.z, s0.w, s1.x, s1.y, s1.z, s1.w};
      const float hv[8] = {h0.x, h0.y, h0.z, h0.w, h1.x, h1.y, h1.z, h1.w};
#pragma unroll
      for (int j = 0; j < 8; ++j) {
        a0[j] = (short)bf_hi(fmaxf(fmaf(bf_f((ushort)a0[j]), sv[j], hv[j]), 0.f));
        a1[j] = (short)bf_hi(fmaxf(fmaf(bf_f((ushort)a1[j]), sv[j], hv[j]), 0.f));
      }
    }
#pragma unroll
    for (int nf = 0; nf < 4; ++nf) {
      const int brow = nf * 16 + lr;
      const int off = (brow * 256 + (c * 4 + lg) * 16) ^ ((lr & 7) << 4);
      const short8v bh = *(const short8v*)(BhB + off);
      const short8v bl = *(const short8v*)(BlB + off);
      acc[0][nf] = __builtin_amdgcn_mfma_f32_16x16x32_bf16(a0, bh, acc[0][nf], 0, 0, 0);
      acc[1][nf] = __builtin_amdgcn_mfma_f32_16x16x32_bf16(a1, bh, acc[1][nf], 0, 0, 0);
      acc[0][nf] = __builtin_amdgcn_mfma_f32_16x16x32_bf16(a0, bl, acc[0][nf], 0, 0, 0);
      acc[1][nf] = __builtin_amdgcn_mfma_f32_16x16x32_bf16(a1, bl, acc[1][nf], 0, 0, 0);
    }
  }
  __builtin_amdgcn_s_setprio(0);

  // ---- epilogue: acc -> LDS bounce; stats partials ----
  float mrow[2][4];
#pragma unroll
  for (int mf = 0; mf < 2; ++mf)
#pragma unroll
    for (int rr = 0; rr < 4; ++rr) {
      const int row = rowBase + w * 32 + mf * 16 + lg * 4 + rr;
      float m = 0.f;
      if (row < nrows) m = MASKED ? ((tmask[row] > 0) ? 1.f : 0.f) : 1.f;
      mrow[mf][rr] = m;
    }
  __syncthreads();  // all waves done reading B
  ushort* Cs = SB;                      // [128][72]
  float* Sred = (float*)(SB + 9216);    // [4][64]
  float* Sq = Sred + 256;               // [4][64]
#pragma unroll
  for (int nf = 0; nf < 4; ++nf) {
    const int col = nf * 16 + lr;
    const float bcol = bias[cBase + col];
    float ps = 0.f, pq = 0.f;
#pragma unroll
    for (int mf = 0; mf < 2; ++mf) {
      const f32x4 vv = acc[mf][nf];
#pragma unroll
      for (int rr = 0; rr < 4; ++rr) {
        const float o = vv[rr] + bcol;
        const int rl = w * 32 + mf * 16 + lg * 4 + rr;
        Cs[rl * 72 + col] = bf_hi(o);
        const float mo = mrow[mf][rr] * o;
        ps += mo;
        pq += mo * o;
      }
    }
    ps += __shfl_xor(ps, 16);
    ps += __shfl_xor(ps, 32);
    pq += __shfl_xor(pq, 16);
    pq += __shfl_xor(pq, 32);
    if (lg == 0) {
      Sred[w * 64 + col] = ps;
      Sq[w * 64 + col] = pq;
    }
  }
  __syncthreads();
  {
    const int rl = tid >> 1, half = tid & 1;
    const int grow = rowBase + rl;
    if (grow < nrows) {
      ushort* dstp = C + (size_t)grow * 128 + cBase + half * 32;
      const ushort* srcp = Cs + rl * 72 + half * 32;
#pragma unroll
      for (int j = 0; j < 4; ++j)
        *(short8v*)(dstp + j * 8) = *(const short8v*)(srcp + j * 8);
    }
  }
  if (tid < 64) {
    float s = 0.f;
#pragma unroll
    for (int q = 0; q < 4; ++q) s += Sred[q * 64 + tid];
    atomicAdd(&statsOut[rep * 512 + cBase + tid], s);
  } else if (tid < 128) {
    float s = 0.f;
#pragma unroll
    for (int q = 0; q < 4; ++q) s += Sq[q * 64 + tid - 64];
    atomicAdd(&statsOut[rep * 512 + 256 + cBase + tid - 64], s);
  }
}

// ---------------------------------------------------------------------------
// FUSED agg+GEMM1: A fragments computed on the fly from CSR message passing.
// Edge walks for row0/row1 merged into ONE predicated loop -> 2 independent
// pairs-load chains + 8 independent x-gathers in flight per iteration.
// ---------------------------------------------------------------------------
__global__ __launch_bounds__(256, 4) void gemm_agg(
    const ushort* __restrict__ x, const ushort* __restrict__ feat,
    const int* __restrict__ offs, const int2* __restrict__ pairs,
    const float* __restrict__ deps, int layer, const ushort* __restrict__ WTh,
    const ushort* __restrict__ WTl, const float* __restrict__ bias,
    ushort* __restrict__ C, float* __restrict__ statsOut,
    int* __restrict__ tmask, int nrows) {
  __shared__ ushort SB[16384];
  ushort* Bh = SB;
  ushort* Bl = SB + 8192;
  const int tid = threadIdx.x;
  const int w = tid >> 6, lane = tid & 63, lr = lane & 15, lg = lane >> 4;
  const int rt = blockIdx.x >> 1, ct = blockIdx.x & 1;
  const int rowBase = rt * 128, cBase = ct * 64;
  const int rep = blockIdx.x & (NREP - 1);

  // ---- stage B once ----
  {
    const int cc = tid >> 2;
    const ushort* sH = WTh + (size_t)(cBase + cc) * 128;
    const ushort* sL = WTl + (size_t)(cBase + cc) * 128;
    char* BhB = (char*)Bh;
    char* BlB = (char*)Bl;
#pragma unroll
    for (int i = 0; i < 4; ++i) {
      const int slot = (tid & 3) * 4 + i;
      const int off = (cc * 256 + slot * 16) ^ ((cc & 7) << 4);
      *(short8v*)(BhB + off) = *(const short8v*)(sH + slot * 8);
      *(short8v*)(BlB + off) = *(const short8v*)(sL + slot * 8);
    }
  }

  const float ce = 1.f + deps[layer];
  const int row0 = rowBase + w * 32 + lr;
  const int row1 = row0 + 16;
  int o0a = 0, o1a = 0, o0b = 0, o1b = 0;
  if (row0 < nrows) {
    o0a = offs[layer * Nn + row0];
    o1a = offs[layer * Nn + row0 + 1];
  }
  if (row1 < nrows) {
    o0b = offs[layer * Nn + row1];
    o1b = offs[layer * Nn + row1 + 1];
  }
  if (lg == 0) {
    if (row0 < nrows) tmask[row0] = (o1a > o0a) ? 1 : 0;
    if (row1 < nrows) tmask[row1] = (o1b > o0b) ? 1 : 0;
  }

  short8v ar0[4], ar1[4];
  {
    float a0[4][8], a1[4][8];
#pragma unroll
    for (int c = 0; c < 4; ++c)
#pragma unroll
      for (int j = 0; j < 8; ++j) {
        a0[c][j] = 0.f;
        a1[c][j] = 0.f;
      }
    int pa = o0a, pb = o0b;
    while (pa < o1a || pb < o1b) {
      int2 prA = make_int2(0, 0), prB = make_int2(0, 0);
      if (pa < o1a) prA = pairs[pa];
      if (pb < o1b) prB = pairs[pb];
      const float wA = __int_as_float(prA.y);
      const float wB = __int_as_float(prB.y);
      const ushort* xrA = x + (size_t)prA.x * 128 + lg * 8;
      const ushort* xrB = x + (size_t)prB.x * 128 + lg * 8;
      short8v xvA[4], xvB[4];
#pragma unroll
      for (int c = 0; c < 4; ++c) {
        xvA[c] = *(const short8v*)(xrA + c * 32);
        xvB[c] = *(const short8v*)(xrB + c * 32);
      }
#pragma unroll
      for (int c = 0; c < 4; ++c)
#pragma unroll
        for (int j = 0; j < 8; ++j) {
          a0[c][j] = fmaf(wA, bf_f((ushort)xvA[c][j]), a0[c][j]);
          a1[c][j] = fmaf(wB, bf_f((ushort)xvB[c][j]), a1[c][j]);
        }
      ++pa;
      ++pb;
    }
    // self-loop feature terms (both rows, loads independent)
    {
      const ushort* frA = feat + (size_t)row0 * 128 + lg * 8;
      const ushort* frB = feat + (size_t)row1 * 128 + lg * 8;
      const bool ta = o1a > o0a, tb = o1b > o0b;
#pragma unroll
      for (int c = 0; c < 4; ++c) {
        short8v fA = {0, 0, 0, 0, 0, 0, 0, 0};
        short8v fB = {0, 0, 0, 0, 0, 0, 0, 0};
        if (ta) fA = *(const short8v*)(frA + c * 32);
        if (tb) fB = *(const short8v*)(frB + c * 32);
#pragma unroll
        for (int j = 0; j < 8; ++j) {
          a0[c][j] = fmaf(ta ? ce : 0.f, bf_f((ushort)fA[j]), a0[c][j]);
          a1[c][j] = fmaf(tb ? ce : 0.f, bf_f((ushort)fB[j]), a1[c][j]);
        }
      }
    }
#pragma unroll
    for (int c = 0; c < 4; ++c)
#pragma unroll
      for (int j = 0; j < 8; ++j) {
        ar0[c][j] = (short)bf_hi(a0[c][j]);
        ar1[c][j] = (short)bf_hi(a1[c][j]);
      }
  }
  __syncthreads();

  const f32x4 fzero = {0.f, 0.f, 0.f, 0.f};
  f32x4 acc[2][4];
#pragma unroll
  for (int i = 0; i < 2; ++i)
#pragma unroll
    for (int j = 0; j < 4; ++j) acc[i][j] = fzero;

  const char* BhB = (const char*)Bh;
  const char* BlB = (const char*)Bl;
  __builtin_amdgcn_s_setprio(1);
#pragma unroll
  for (int c = 0; c < 4; ++c) {
    const short8v a0 = ar0[c], a1 = ar1[c];
#pragma unroll
    for (int nf = 0; nf < 4; ++nf) {
      const int brow = nf * 16 + lr;
      const int off = (brow * 256 + (c * 4 + lg) * 16) ^ ((lr & 7) << 4);
      const short8v bh = *(const short8v*)(BhB + off);
      const short8v bl = *(const short8v*)(BlB + off);
      acc[0][nf] = __builtin_amdgcn_mfma_f32_16x16x32_bf16(a0, bh, acc[0][nf], 0, 0, 0);
      acc[1][nf] = __builtin_amdgcn_mfma_f32_16x16x32_bf16(a1, bh, acc[1][nf], 0, 0, 0);
      acc[0][nf] = __builtin_amdgcn_mfma_f32_16x16x32_bf16(a0, bl, acc[0][nf], 0, 0, 0);
      acc[1][nf] = __builtin_amdgcn_mfma_f32_16x16x32_bf16(a1, bl, acc[1][nf], 0, 0, 0);
    }
  }
  __builtin_amdgcn_s_setprio(0);

  // ---- epilogue: mask via shfl of per-row deg flags ----
  const float dga = (o1a > o0a) ? 1.f : 0.f;
  const float dgb = (o1b > o0b) ? 1.f : 0.f;
  float mrow[2][4];
#pragma unroll
  for (int rr = 0; rr < 4; ++rr) {
    const int srcl = lg * 4 + rr;  // lane holding that row's deg flag
    mrow[0][rr] = __shfl(dga, srcl, 64);
    mrow[1][rr] = __shfl(dgb, srcl, 64);
  }
#pragma unroll
  for (int mf = 0; mf < 2; ++mf)
#pragma unroll
    for (int rr = 0; rr < 4; ++rr) {
      const int row = rowBase + w * 32 + mf * 16 + lg * 4 + rr;
      if (row >= nrows) mrow[mf][rr] = 0.f;
    }
  __syncthreads();
  ushort* Cs = SB;                    // [128][72]
  float* Sred = (float*)(SB + 9216);  // [4][64]
  float* Sq = Sred + 256;
#pragma unroll
  for (int nf = 0; nf < 4; ++nf) {
    const int col = nf * 16 + lr;
    const float bcol = bias[cBase + col];
    float ps = 0.f, pq = 0.f;
#pragma unroll
    for (int mf = 0; mf < 2; ++mf) {
      const f32x4 vv = acc[mf][nf];
#pragma unroll
      for (int rr = 0; rr < 4; ++rr) {
        const float o = vv[rr] + bcol;
        const int rl = w * 32 + mf * 16 + lg * 4 + rr;
        Cs[rl * 72 + col] = bf_hi(o);
        const float mo = mrow[mf][rr] * o;
        ps += mo;
        pq += mo * o;
      }
    }
    ps += __shfl_xor(ps, 16);
    ps += __shfl_xor(ps, 32);
    pq += __shfl_xor(pq, 16);
    pq += __shfl_xor(pq, 32);
    if (lg == 0) {
      Sred[w * 64 + col] = ps;
      Sq[w * 64 + col] = pq;
    }
  }
  __syncthreads();
  {
    const int rl = tid >> 1, half = tid & 1;
    const int grow = rowBase + rl;
    if (grow < nrows) {
      ushort* dstp = C + (size_t)grow * 128 + cBase + half * 32;
      const ushort* srcp = Cs + rl * 72 + half * 32;
#pragma unroll
      for (int j = 0; j < 4; ++j)
        *(short8v*)(dstp + j * 8) = *(const short8v*)(srcp + j * 8);
    }
  }
  if (tid < 64) {
    float s = 0.f;
#pragma unroll
    for (int q = 0; q < 4; ++q) s += Sred[q * 64 + tid];
    atomicAdd(&statsOut[rep * 512 + cBase + tid], s);
  } else if (tid < 128) {
    float s = 0.f;
#pragma unroll
    for (int q = 0; q < 4; ++q) s += Sq[q * 64 + tid - 64];
    atomicAdd(&statsOut[rep * 512 + 256 + cBase + tid - 64], s);
  }
}

// ---------------------------------------------------------------------------
// GEMM #1: fp32 A (dag_x), K=64, hi/lo-split A (3 MFMAs). Same epilogue.
// ---------------------------------------------------------------------------
__global__ __launch_bounds__(256, 4) void gemm_f32a(
    const float* __restrict__ A, const ushort* __restrict__ WTh,
    const ushort* __restrict__ WTl, const float* __restrict__ bias,
    ushort* __restrict__ C, float* __restrict__ statsOut, int nrows) {
  __shared__ ushort SB[11264];  // Bh[4096] | Bl[4096]; reused Cs[128][72]+red
  ushort* Bh = SB;
  ushort* Bl = SB + 4096;
  const int tid = threadIdx.x;
  const int w = tid >> 6, lane = tid & 63, lr = lane & 15, lg = lane >> 4;
  const int rt = blockIdx.x >> 1, ct = blockIdx.x & 1;
  const int rowBase = rt * 128, cBase = ct * 64;
  const int rep = blockIdx.x & (NREP - 1);

  {
    const int cc = tid >> 2;
    const ushort* sH = WTh + (size_t)(cBase + cc) * 64;
    const ushort* sL = WTl + (size_t)(cBase + cc) * 64;
    char* BhB = (char*)Bh;
    char* BlB = (char*)Bl;
#pragma unroll
    for (int i = 0; i < 2; ++i) {
      const int slot = (tid & 3) * 2 + i;
      const int off = (cc * 128 + slot * 16) ^ ((cc & 7) << 4);
      *(short8v*)(BhB + off) = *(const short8v*)(sH + slot * 8);
      *(short8v*)(BlB + off) = *(const short8v*)(sL + slot * 8);
    }
  }

  const int row0 = rowBase + w * 32 + lr;
  const int row1 = row0 + 16;
  const bool ok0 = row0 < nrows, ok1 = row1 < nrows;
  const float4 fz4 = make_float4(0.f, 0.f, 0.f, 0.f);
  const float* aP0 = A + (size_t)row0 * 64 + lg * 8;
  const float* aP1 = A + (size_t)row1 * 64 + lg * 8;
  float4 ar0[2][2], ar1[2][2];
#pragma unroll
  for (int c = 0; c < 2; ++c) {
    ar0[c][0] = ok0 ? *(const float4*)(aP0 + c * 32) : fz4;
    ar0[c][1] = ok0 ? *(const float4*)(aP0 + c * 32 + 4) : fz4;
    ar1[c][0] = ok1 ? *(const float4*)(aP1 + c * 32) : fz4;
    ar1[c][1] = ok1 ? *(const float4*)(aP1 + c * 32 + 4) : fz4;
  }
  __syncthreads();

  const f32x4 fzero = {0.f, 0.f, 0.f, 0.f};
  f32x4 acc[2][4];
#pragma unroll
  for (int i = 0; i < 2; ++i)
#pragma unroll
    for (int j = 0; j < 4; ++j) acc[i][j] = fzero;

  const char* BhB = (const char*)Bh;
  const char* BlB = (const char*)Bl;
  __builtin_amdgcn_s_setprio(1);
#pragma unroll
  for (int c = 0; c < 2; ++c) {
    const float v0[8] = {ar0[c][0].x, ar0[c][0].y, ar0[c][0].z, ar0[c][0].w,
                         ar0[c][1].x, ar0[c][1].y, ar0[c][1].z, ar0[c][1].w};
    const float v1[8] = {ar1[c][0].x, ar1[c][0].y, ar1[c][0].z, ar1[c][0].w,
                         ar1[c][1].x, ar1[c][1].y, ar1[c][1].z, ar1[c][1].w};
    short8v a0h, a0l, a1h, a1l;
#pragma unroll
    for (int j = 0; j < 8; ++j) {
      ushort hh = bf_hi(v0[j]);
      a0h[j] = (short)hh;
      a0l[j] = (short)bf_hi(v0[j] - bf_f(hh));
      hh = bf_hi(v1[j]);
      a1h[j] = (short)hh;
      a1l[j] = (short)bf_hi(v1[j] - bf_f(hh));
    }
#pragma unroll
    for (int nf = 0; nf < 4; ++nf) {
      const int brow = nf * 16 + lr;
      const int off = (brow * 128 + (c * 4 + lg) * 16) ^ ((lr & 7) << 4);
      const short8v bh = *(const short8v*)(BhB + off);
      const short8v bl = *(const short8v*)(BlB + off);
      acc[0][nf] = __builtin_amdgcn_mfma_f32_16x16x32_bf16(a0h, bh, acc[0][nf], 0, 0, 0);
      acc[1][nf] = __builtin_amdgcn_mfma_f32_16x16x32_bf16(a1h, bh, acc[1][nf], 0, 0, 0);
      acc[0][nf] = __builtin_amdgcn_mfma_f32_16x16x32_bf16(a0l, bh, acc[0][nf], 0, 0, 0);
      acc[1][nf] = __builtin_amdgcn_mfma_f32_16x16x32_bf16(a1l, bh, acc[1][nf], 0, 0, 0);
      acc[0][nf] = __builtin_amdgcn_mfma_f32_16x16x32_bf16(a0h, bl, acc[0][nf], 0, 0, 0);
      acc[1][nf] = __builtin_amdgcn_mfma_f32_16x16x32_bf16(a1h, bl, acc[1][nf], 0, 0, 0);
    }
  }
  __builtin_amdgcn_s_setprio(0);

  __syncthreads();
  ushort* Cs = SB;                    // [128][72]
  float* Sred = (float*)(SB + 9216);  // [4][64]
  float* Sq = Sred + 256;
#pragma unroll
  for (int nf = 0; nf < 4; ++nf) {
    const int col = nf * 16 + lr;
    const float bcol = bias[cBase + col];
    float ps = 0.f, pq = 0.f;
#pragma unroll
    for (int mf = 0; mf < 2; ++mf) {
      const f32x4 vv = acc[mf][nf];
#pragma unroll
      for (int rr = 0; rr < 4; ++rr) {
        const float o = vv[rr] + bcol;
        const int rl = w * 32 + mf * 16 + lg * 4 + rr;
        Cs[rl * 72 + col] = bf_hi(o);
        const int row = rowBase + rl;
        const float m = (row < nrows) ? 1.f : 0.f;
        const float mo = m * o;
        ps += mo;
        pq += mo * o;
      }
    }
    ps += __shfl_xor(ps, 16);
    ps += __shfl_xor(ps, 32);
    pq += __shfl_xor(pq, 16);
    pq += __shfl_xor(pq, 32);
    if (lg == 0) {
      Sred[w * 64 + col] = ps;
      Sq[w * 64 + col] = pq;
    }
  }
  __syncthreads();
  {
    const int rl = tid >> 1, half = tid & 1;
    const int grow = rowBase + rl;
    if (grow < nrows) {
      ushort* dstp = C + (size_t)grow * 128 + cBase + half * 32;
      const ushort* srcp = Cs + rl * 72 + half * 32;
#pragma unroll
      for (int j = 0; j < 4; ++j)
        *(short8v*)(dstp + j * 8) = *(const short8v*)(srcp + j * 8);
    }
  }
  if (tid < 64) {
    float s = 0.f;
#pragma unroll
    for (int q = 0; q < 4; ++q) s += Sred[q * 64 + tid];
    atomicAdd(&statsOut[rep * 512 + cBase + tid], s);
  } else if (tid < 128) {
    float s = 0.f;
#pragma unroll
    for (int q = 0; q < 4; ++q) s += Sq[q * 64 + tid - 64];
    atomicAdd(&statsOut[rep * 512 + 256 + cBase + tid - 64], s);
  }
}

// Weight transpose + hi/lo split: 8 slots of 32768 ushorts (hi, lo@+16384)
__global__ __launch_bounds__(256) void wsplit_kernel(
    const float* __restrict__ W1, const float* __restrict__ W2,
    const float* __restrict__ dW1, const float* __restrict__ dW2,
    ushort* __restrict__ wsT) {
  const int t = blockIdx.x * 256 + threadIdx.x;
  const int slot = t >> 14;
  const int idx = t & 16383;
  if (slot >= 8) return;
  const int Ks = (slot == 0) ? 64 : 128;
  if (idx >= 128 * Ks) return;
  const int c = idx / Ks;
  const int k = idx - c * Ks;
  float v;
  if (slot == 0) v = W1[k * 128 + c];
  else if (slot == 1) v = W2[k * 128 + c];
  else if (slot < 5) v = dW1[(slot - 2) * 16384 + k * 128 + c];
  else v = dW2[(slot - 5) * 16384 + k * 128 + c];
  const ushort h = bf_hi(v);
  const ushort l = bf_hi(v - bf_f(h));
  wsT[slot * 32768 + c * Ks + k] = h;
  wsT[slot * 32768 + 16384 + c * Ks + k] = l;
}

// feat = relu(y*sc+sh); also zeroes x (replaces the xbuf memset dispatch).
__global__ __launch_bounds__(256) void normrelu_kernel(
    const ushort* __restrict__ in, const float* __restrict__ stats,
    const float* __restrict__ g, const float* __restrict__ be, float cntFixed,
    ushort* __restrict__ outp, ushort* __restrict__ xz) {
  __shared__ float ssS[256];
  compute_ss_lds(stats, g, be, cntFixed, ssS);
  __syncthreads();
  const int tid = threadIdx.x;
  const int c4 = (tid & 31) * 4;
  const float4 sc = *(const float4*)&ssS[c4];
  const float4 sh = *(const float4*)&ssS[128 + c4];
  const int rowBase = blockIdx.x * 64;
  const ushort4 z4 = make_ushort4(0, 0, 0, 0);
#pragma unroll
  for (int it = 0; it < 8; ++it) {
    const int row = rowBase + it * 8 + (tid >> 5);
    if (row >= Nn) continue;
    const size_t idx = (size_t)row * 32 + (tid & 31);
    const ushort4 v = ((const ushort4*)in)[idx];
    ushort4 o;
    o.x = bf_hi(fmaxf(fmaf(bf_f(v.x), sc.x, sh.x), 0.f));
    o.y = bf_hi(fmaxf(fmaf(bf_f(v.y), sc.y, sh.y), 0.f));
    o.z = bf_hi(fmaxf(fmaf(bf_f(v.z), sc.z, sh.z), 0.f));
    o.w = bf_hi(fmaxf(fmaf(bf_f(v.w), sc.w, sh.w), 0.f));
    ((ushort4*)outp)[idx] = o;
    ((ushort4*)xz)[idx] = z4;
  }
}

// x += (tmask>0) * relu(y*sc+sh)
__global__ __launch_bounds__(256) void normrelu_acc_kernel(
    const ushort* __restrict__ in, const float* __restrict__ stats,
    const float* __restrict__ g, const float* __restrict__ be,
    const float* __restrict__ cntPtr, const int* __restrict__ tmask,
    ushort* __restrict__ x) {
  __shared__ float ssS[256];
  compute_ss_lds(stats, g, be, fmaxf(cntPtr[0], 1.f), ssS);
  __syncthreads();
  const int tid = threadIdx.x;
  const int c4 = (tid & 31) * 4;
  const float4 sc = *(const float4*)&ssS[c4];
  const float4 sh = *(const float4*)&ssS[128 + c4];
  const int rowBase = blockIdx.x * 64;
#pragma unroll
  for (int it = 0; it < 8; ++it) {
    const int row = rowBase + it * 8 + (tid >> 5);
    if (row >= Nn || tmask[row] <= 0) continue;
    const size_t idx = (size_t)row * 32 + (tid & 31);
    const ushort4 v = ((const ushort4*)in)[idx];
    ushort4 xo = ((const ushort4*)x)[idx];
    xo.x = bf_hi(bf_f(xo.x) + fmaxf(fmaf(bf_f(v.x), sc.x, sh.x), 0.f));
    xo.y = bf_hi(bf_f(xo.y) + fmaxf(fmaf(bf_f(v.y), sc.y, sh.y), 0.f));
    xo.z = bf_hi(bf_f(xo.z) + fmaxf(fmaf(bf_f(v.z), sc.z, sh.z), 0.f));
    xo.w = bf_hi(bf_f(xo.w) + fmaxf(fmaf(bf_f(v.w), sc.w, sh.w), 0.f));
    ((ushort4*)x)[idx] = xo;
  }
}

__global__ __launch_bounds__(256) void scatter_leaves_kernel(
    const int* __restrict__ leaves, const ushort* __restrict__ feat,
    ushort* __restrict__ x, int nl) {
  const int gid = blockIdx.x * 256 + threadIdx.x;
  const int j = gid >> 5;
  if (j >= nl) return;
  const int node = leaves[j];
  const int c4 = (gid & 31) * 4;
  *(ushort4*)&x[(size_t)node * 128 + c4] =
      *(const ushort4*)&feat[(size_t)node * 128 + c4];
}

// ---------------- CSR build ----------------
__global__ __launch_bounds__(256) void deg_count_kernel(
    const int* __restrict__ dst, const int* __restrict__ lmask,
    int* __restrict__ cnts) {
  const int e = blockIdx.x * 256 + threadIdx.x;
  if (e >= Ee) return;
  atomicAdd(&cnts[lmask[e] * Nn + dst[e]], 1);
}

// scan1 + fused per-layer target count (nodes with deg>0) -> tcountf[0..2]
__global__ __launch_bounds__(256) void scan1_kernel(const int* __restrict__ in,
                                                    int* __restrict__ out,
                                                    int* __restrict__ bsum,
                                                    float* __restrict__ tcountf,
                                                    int n) {
  __shared__ int lds[256];
  __shared__ float tcS[3];
  const int tid = threadIdx.x;
  const int base = blockIdx.x * 2048 + tid * 8;
  int vals[8];
  int tsum = 0;
  float t0 = 0.f, t1 = 0.f, t2 = 0.f;
#pragma unroll
  for (int j = 0; j < 8; ++j) {
    const int i = base + j;
    const int v = (i < n) ? in[i] : 0;
    if (v > 0) {
      if (i < Nn) t0 += 1.f;
      else if (i < 2 * Nn) t1 += 1.f;
      else t2 += 1.f;
    }
    vals[j] = tsum;
    tsum += v;
  }
  lds[tid] = tsum;
  if (tid < 3) tcS[tid] = 0.f;
  __syncthreads();
  if (t0 != 0.f) atomicAdd(&tcS[0], t0);
  if (t1 != 0.f) atomicAdd(&tcS[1], t1);
  if (t2 != 0.f) atomicAdd(&tcS[2], t2);
  for (int off = 1; off < 256; off <<= 1) {
    const int y = (tid >= off) ? lds[tid - off] : 0;
    __syncthreads();
    lds[tid] += y;
    __syncthreads();
  }
  const int texcl = (tid > 0) ? lds[tid - 1] : 0;
#pragma unroll
  for (int j = 0; j < 8; ++j)
    if (base + j < n) out[base + j] = texcl + vals[j];
  if (tid == 255) bsum[blockIdx.x] = lds[255];
  __syncthreads();
  if (tid < 3 && tcS[tid] != 0.f) atomicAdd(&tcountf[tid], tcS[tid]);
}

// scan3 with scan2 fused: each block redundantly scans the 147 block sums.
__global__ __launch_bounds__(256) void scan3_kernel(int* __restrict__ out,
                                                    int* __restrict__ cursor,
                                                    const int* __restrict__ bsum,
                                                    int nb, int n, int etot) {
  __shared__ int bs[256];
  const int tid = threadIdx.x;
  const int v = (tid < nb) ? bsum[tid] : 0;
  bs[tid] = v;
  __syncthreads();
  for (int off = 1; off < 256; off <<= 1) {
    const int y = (tid >= off) ? bs[tid - off] : 0;
    __syncthreads();
    bs[tid] += y;
    __syncthreads();
  }
  const int i = blockIdx.x * 256 + tid;
  if (i >= n) return;
  const int b = i >> 11;
  const int excl = (b > 0) ? bs[b - 1] : 0;
  const int val = out[i] + excl;
  out[i] = val;
  cursor[i] = val;
  if (i == n - 1) out[n] = etot;
}

__global__ __launch_bounds__(256) void csr_fill_kernel(
    const int* __restrict__ src, const int* __restrict__ dst,
    const float* __restrict__ mult, const int* __restrict__ lmask,
    int* __restrict__ cursor, int2* __restrict__ pairs) {
  const int e = blockIdx.x * 256 + threadIdx.x;
  if (e >= Ee) return;
  const int slot = atomicAdd(&cursor[lmask[e] * Nn + dst[e]], 1);
  pairs[slot] = make_int2(src[e], __float_as_int(mult[e]));
}

// ---------------- readout: replicated-bucket counting-sort pool -----------
__global__ __launch_bounds__(256) void phist_kernel(const int* __restrict__ ridx,
                                                    const int* __restrict__ batch,
                                                    int* __restrict__ cnt, int n) {
  const int i = blockIdx.x * 256 + threadIdx.x;
  if (i >= n) return;
  atomicAdd(&cnt[batch[ridx[i]] * PR + (i & (PR - 1))], 1);
}

// exclusive scan over 256*PR = 8192 buckets (single block, 32 elems/thread)
__global__ void pscan_kernel(int* __restrict__ cnt, int* __restrict__ cur) {
  __shared__ int l[256];
  const int t = threadIdx.x;
  const int base = t * 32;
  int vals[32];
  int tsum = 0;
#pragma unroll
  for (int j = 0; j < 32; ++j) {
    const int v = cnt[base + j];
    vals[j] = tsum;
    tsum += v;
  }
  l[t] = tsum;
  __syncthreads();
  for (int off = 1; off < 256; off <<= 1) {
    const int y = (t >= off) ? l[t - off] : 0;
    __syncthreads();
    l[t] += y;
    __syncthreads();
  }
  const int excl = (t > 0) ? l[t - 1] : 0;
#pragma unroll
  for (int j = 0; j < 32; ++j) {
    const int v = excl + vals[j];
    cnt[base + j] = v;
    cur[base + j] = v;
  }
}

__global__ __launch_bounds__(256) void pfill_kernel(const int* __restrict__ ridx,
                                                    const int* __restrict__ batch,
                                                    int* __restrict__ cur,
                                                    int* __restrict__ sorted,
                                                    int n) {
  const int i = blockIdx.x * 256 + threadIdx.x;
  if (i >= n) return;
  const int node = ridx[i];
  const int slot = atomicAdd(&cur[batch[node] * PR + (i & (PR - 1))], 1);
  sorted[slot] = node;
}

// Parallel pool: 8 slices per graph -> Ppart[g*8+slice][128] (no atomics)
__global__ __launch_bounds__(256) void ppool_kernel(const int* __restrict__ sorted,
                                                    const int* __restrict__ offs,
                                                    const ushort* __restrict__ x,
                                                    float* __restrict__ Ppart,
                                                    int n) {
  __shared__ float part[4][256];
  const int bid = blockIdx.x;
  const int g = bid >> 3, slice = bid & (PSL - 1);
  const int w = threadIdx.x >> 6;
  const int lane = threadIdx.x & 63;
  const int o0 = offs[g * PR];
  const int o1 = (g < Gg - 1) ? offs[(g + 1) * PR] : n;
  float ax = 0.f, ay = 0.f;
  for (int p = o0 + slice * 4 + w; p < o1; p += 32) {
    const int node = sorted[p];
    const ushort2 xv = *(const ushort2*)&x[(size_t)node * 128 + lane * 2];
    ax += bf_f(xv.x);
    ay += bf_f(xv.y);
  }
  part[w][lane * 2] = ax;
  part[w][lane * 2 + 1] = ay;
  __syncthreads();
  if (threadIdx.x < 128) {
    const int c = threadIdx.x;
    Ppart[(size_t)bid * 128 + c] =
        part[0][c] + part[1][c] + part[2][c] + part[3][c];
  }
}

// Fused preduce + final linear: out[g][t] = 0.25*sum_slices(Ppart)@Wl + bl
__global__ __launch_bounds__(128) void pout_kernel(
    const float* __restrict__ Ppart, const float* __restrict__ Wl,
    const float* __restrict__ bl, float* __restrict__ out) {
  __shared__ float Pl[128];
  const int g = blockIdx.x;
  const int t = threadIdx.x;  // 128
  float s = 0.f;
#pragma unroll
  for (int r = 0; r < PSL; ++r) s += Ppart[(size_t)(g * PSL + r) * 128 + t];
  Pl[t] = s * 0.25f;
  __syncthreads();
  if (t < Tt) {
    float acc = 0.f;
    for (int c = 0; c < 128; ++c) acc += Pl[c] * Wl[c * Tt + t];
    out[g * Tt + t] = acc + bl[t];
  }
}

extern "C" void kernel_launch(void* const* d_in, const int* in_sizes, int n_in,
                              void* d_out, int out_size, void* d_ws,
                              size_t ws_size, hipStream_t stream) {
  const float* dag_x = (const float*)d_in[0];
  const int* eidx = (const int*)d_in[1];
  const int* src = eidx;
  const int* dst = eidx + Ee;
  const float* mult = (const float*)d_in[2];
  const int* lmask = (const int*)d_in[3];
  const int* batch = (const int*)d_in[4];
  const int* leaves = (const int*)d_in[5];
  const int* readouts = (const int*)d_in[6];
  const float* W1 = (const float*)d_in[7];
  const float* b1 = (const float*)d_in[8];
  const float* g1 = (const float*)d_in[9];
  const float* be1 = (const float*)d_in[10];
  const float* W2 = (const float*)d_in[11];
  const float* b2 = (const float*)d_in[12];
  const float* g2 = (const float*)d_in[13];
  const float* be2 = (const float*)d_in[14];
  const float* dW1 = (const float*)d_in[15];
  const float* db1 = (const float*)d_in[16];
  const float* dg1 = (const float*)d_in[17];
  const float* dbe1 = (const float*)d_in[18];
  const float* dW2 = (const float*)d_in[19];
  const float* db2 = (const float*)d_in[20];
  const float* dg2 = (const float*)d_in[21];
  const float* dbe2 = (const float*)d_in[22];
  const float* deps = (const float*)d_in[23];
  const float* Wl = (const float*)d_in[24];
  const float* bl = (const float*)d_in[25];
  float* out = (float*)d_out;

  const size_t ND = (size_t)Nn * Dd;
  ushort* feat = (ushort*)d_ws;           // ND bf16
  ushort* xbuf = feat + ND;               // ND bf16
  ushort* Abuf = xbuf + ND;               // ND bf16
  ushort* Bbuf = Abuf + ND;               // ND bf16 (gemm ping-pong)
  float* statsAll = (float*)(Bbuf + ND);  // 8 slots x [16][512]
  float* tcountf = statsAll + 8 * 8192;   // 8 (4 used) -- adjacent for memset
  int* tmask = (int*)(tcountf + 8);       // N
  ushort* wsT = (ushort*)(tmask + Nn);    // 262144 (8 weight slots, hi+lo)
  int* offs = (int*)(wsT + 262144);       // 3N+4
  int2* pairs = (int2*)(offs + 3 * Nn + 4);  // E pairs (src, mult)

  // transient overlays (xbuf region before it's initialized):
  int* cnts = (int*)xbuf;                 // 3N
  int* cursor = cnts + 3 * Nn;            // 3N
  int* bsum = cursor + 3 * Nn;            // 147
  const int nridx = in_sizes[6];          // 80000
  const int nleaves = in_sizes[5];        // 50000
  // pool overlays (Abuf dead by readout):
  int* pcnt = (int*)Abuf;                 // 256*PR (becomes offsets)
  int* pcur = pcnt + Gg * PR;             // 256*PR
  int* sorted = pcur + Gg * PR;           // nridx
  float* Ppart = (float*)(sorted + nridx);  // 2048*128

  dim3 blk(256);
  hipMemsetAsync(statsAll, 0, (8 * 8192 + 8) * sizeof(float), stream);
  wsplit_kernel<<<512, blk, 0, stream>>>(W1, W2, dW1, dW2, wsT);

  // ---- CSR build (tcount fused into scan1; scan2 fused into scan3) ----
  hipMemsetAsync(cnts, 0, 3 * Nn * sizeof(int), stream);
  deg_count_kernel<<<2344, blk, 0, stream>>>(dst, lmask, cnts);
  scan1_kernel<<<147, blk, 0, stream>>>(cnts, offs, bsum, tcountf, 3 * Nn);
  scan3_kernel<<<1172, blk, 0, stream>>>(offs, cursor, bsum, 147, 3 * Nn, Ee);
  csr_fill_kernel<<<2344, blk, 0, stream>>>(src, dst, mult, lmask, cursor, pairs);

  const int gGemm = 782 * 2;
  // ---- node feature transform ----
  gemm_f32a<<<gGemm, blk, 0, stream>>>(dag_x, wsT, wsT + 16384, b1, Abuf,
                                       statsAll + 0 * 8192, Nn);
  gemm_bf16<true, false><<<gGemm, blk, 0, stream>>>(
      Abuf, wsT + 32768, wsT + 32768 + 16384, b2, statsAll + 0 * 8192, g1, be1,
      nullptr, nullptr, Bbuf, statsAll + 1 * 8192, Nn);
  // feat = relu(bn(y2)); also zeroes xbuf (no memset dispatch)
  normrelu_kernel<<<1563, blk, 0, stream>>>(Bbuf, statsAll + 1 * 8192, g2, be2,
                                            (float)Nn, feat, xbuf);
  scatter_leaves_kernel<<<6250, blk, 0, stream>>>(leaves, feat, xbuf, nleaves);

  // ---- DAG layers (agg fused into gemm1) ----
  for (int layer = 0; layer < Ll; ++layer) {
    const int so1 = (2 + layer) * 32768;
    const int so2 = (5 + layer) * 32768;
    const int po = layer * Dd;
    float* st1 = statsAll + (size_t)(2 + 2 * layer) * 8192;
    float* st2 = statsAll + (size_t)(3 + 2 * layer) * 8192;
    gemm_agg<<<gGemm, blk, 0, stream>>>(xbuf, feat, offs, pairs, deps, layer,
                                        wsT + so1, wsT + so1 + 16384, db1 + po,
                                        Bbuf, st1, tmask, Nn);
    gemm_bf16<true, true><<<gGemm, blk, 0, stream>>>(
        Bbuf, wsT + so2, wsT + so2 + 16384, db2 + po, st1, dg1 + po, dbe1 + po,
        tcountf + layer, tmask, Abuf, st2, Nn);
    normrelu_acc_kernel<<<1563, blk, 0, stream>>>(
        Abuf, st2, dg2 + po, dbe2 + po, tcountf + layer, tmask, xbuf);
  }

  // ---- readout (replicated-bucket counting sort, no float atomics) ----
  hipMemsetAsync(pcnt, 0, Gg * PR * sizeof(int), stream);
  const int gIdx = (nridx + 255) / 256;
  phist_kernel<<<gIdx, blk, 0, stream>>>(readouts, batch, pcnt, nridx);
  pscan_kernel<<<1, blk, 0, stream>>>(pcnt, pcur);
  pfill_kernel<<<gIdx, blk, 0, stream>>>(readouts, batch, pcur, sorted, nridx);
  ppool_kernel<<<Gg * PSL, blk, 0, stream>>>(sorted, pcnt, xbuf, Ppart, nridx);
  pout_kernel<<<Gg, dim3(128), 0, stream>>>(Ppart, Wl, bl, out);
}

// Round 13
// 460.169 us; speedup vs baseline: 1.1311x; 1.0024x over previous
//
#include <hip/hip_runtime.h>

constexpr int Nn = 100000;   // nodes
constexpr int Ee = 600000;   // edges
constexpr int Dd = 128;      // hidden dim
constexpr int Ll = 3;        // DAG layers
constexpr int Gg = 256;      // graphs
constexpr int Tt = 10;       // outputs per graph
constexpr float BN_EPS = 1e-5f;
constexpr int NREP = 16;     // stats replicas (slot = [16][512] floats)
constexpr int PSL = 8;       // pool slices per graph
constexpr int PR = 32;       // counting-sort bucket replicas per graph

typedef __attribute__((ext_vector_type(8))) short short8v;
typedef __attribute__((ext_vector_type(4))) float f32x4;

__device__ inline ushort bf_hi(float f) {
  unsigned u = __float_as_uint(f);
  unsigned r = (u + 0x7FFFu + ((u >> 16) & 1u)) >> 16;
  return (ushort)r;
}
__device__ inline float bf_f(ushort h) {
  return __uint_as_float(((unsigned)h) << 16);
}

// BN scale/shift from a replicated stats slot -> LDS ssS[256] (threads 0..127)
__device__ inline void compute_ss_lds(const float* __restrict__ stats,
                                      const float* __restrict__ g,
                                      const float* __restrict__ be, float cnt,
                                      float* ssS) {
  const int c = threadIdx.x;
  if (c < 128) {
    float S = 0.f, Q = 0.f;
#pragma unroll
    for (int r = 0; r < NREP; ++r) {
      S += stats[r * 512 + c];
      Q += stats[r * 512 + 256 + c];
    }
    const float m = S / cnt;
    const float v = Q / cnt - m * m;
    const float sc = g[c] * rsqrtf(v + BN_EPS);
    ssS[c] = sc;
    ssS[128 + c] = be[c] - m * sc;
  }
}

// ---------------------------------------------------------------------------
// B-resident barrier-free GEMM (bf16 A): C[N][64-slice] = op(A)@W + bias.
// ---------------------------------------------------------------------------
template <bool NORM_A, bool MASKED>
__global__ __launch_bounds__(256, 4) void gemm_bf16(
    const ushort* __restrict__ A, const ushort* __restrict__ WTh,
    const ushort* __restrict__ WTl, const float* __restrict__ bias,
    const float* __restrict__ statsIn, const float* __restrict__ gN,
    const float* __restrict__ beN, const float* __restrict__ cntPtr,
    const int* __restrict__ tmask, ushort* __restrict__ C,
    float* __restrict__ statsOut, int nrows) {
  __shared__ ushort SB[16384];  // Bh[8192] | Bl[8192]; reused: Cs[128][72]+red
  __shared__ float ssS[256];
  ushort* Bh = SB;
  ushort* Bl = SB + 8192;
  const int tid = threadIdx.x;
  const int w = tid >> 6, lane = tid & 63, lr = lane & 15, lg = lane >> 4;
  const int rt = blockIdx.x >> 1, ct = blockIdx.x & 1;
  const int rowBase = rt * 128, cBase = ct * 64;
  const int rep = blockIdx.x & (NREP - 1);

  // ---- stage B once (swizzle: byte ^= (col&7)<<4 within 256B row) ----
  {
    const int cc = tid >> 2;
    const ushort* sH = WTh + (size_t)(cBase + cc) * 128;
    const ushort* sL = WTl + (size_t)(cBase + cc) * 128;
    char* BhB = (char*)Bh;
    char* BlB = (char*)Bl;
#pragma unroll
    for (int i = 0; i < 4; ++i) {
      const int slot = (tid & 3) * 4 + i;
      const int off = (cc * 256 + slot * 16) ^ ((cc & 7) << 4);
      *(short8v*)(BhB + off) = *(const short8v*)(sH + slot * 8);
      *(short8v*)(BlB + off) = *(const short8v*)(sL + slot * 8);
    }
  }
  if (NORM_A) {
    const float cnt = cntPtr ? fmaxf(cntPtr[0], 1.f) : (float)nrows;
    compute_ss_lds(statsIn, gN, beN, cnt, ssS);
  }

  // ---- prefetch all A fragments ----
  const int row0 = rowBase + w * 32 + lr;
  const int row1 = row0 + 16;
  const bool ok0 = row0 < nrows, ok1 = row1 < nrows;
  const short8v szero = {0, 0, 0, 0, 0, 0, 0, 0};
  const ushort* aP0 = A + (size_t)row0 * 128 + lg * 8;
  const ushort* aP1 = A + (size_t)row1 * 128 + lg * 8;
  short8v ar0[4], ar1[4];
#pragma unroll
  for (int c = 0; c < 4; ++c) {
    ar0[c] = ok0 ? *(const short8v*)(aP0 + c * 32) : szero;
    ar1[c] = ok1 ? *(const short8v*)(aP1 + c * 32) : szero;
  }
  __syncthreads();

  const f32x4 fzero = {0.f, 0.f, 0.f, 0.f};
  f32x4 acc[2][4];
#pragma unroll
  for (int i = 0; i < 2; ++i)
#pragma unroll
    for (int j = 0; j < 4; ++j) acc[i][j] = fzero;

  const char* BhB = (const char*)Bh;
  const char* BlB = (const char*)Bl;
  __builtin_amdgcn_s_setprio(1);
#pragma unroll
  for (int c = 0; c < 4; ++c) {
    short8v a0 = ar0[c], a1 = ar1[c];
    if (NORM_A) {
      const int kb = c * 32 + lg * 8;
      const float4 s0 = *(const float4*)&ssS[kb];
      const float4 s1 = *(const float4*)&ssS[kb + 4];
      const float4 h0 = *(const float4*)&ssS[128 + kb];
      const float4 h1 = *(const float4*)&ssS[128 + kb + 4];
      const float sv[8] = {s0.x, s0.y, s0.z, s0.w, s1.x, s1.y, s1.z, s1.w};
      const float hv[8] = {h0.x, h0.y, h0.z, h0.w, h1.x, h1.y, h1.z, h1.w};
#pragma unroll
      for (int j = 0; j < 8; ++j) {
        a0[j] = (short)bf_hi(fmaxf(fmaf(bf_f((ushort)a0[j]), sv[j], hv[j]), 0.f));
        a1[j] = (short)bf_hi(fmaxf(fmaf(bf_f((ushort)a1[j]), sv[j], hv[j]), 0.f));
      }
    }
#pragma unroll
    for (int nf = 0; nf < 4; ++nf) {
      const int brow = nf * 16 + lr;
      const int off = (brow * 256 + (c * 4 + lg) * 16) ^ ((lr & 7) << 4);
      const short8v bh = *(const short8v*)(BhB + off);
      const short8v bl = *(const short8v*)(BlB + off);
      acc[0][nf] = __builtin_amdgcn_mfma_f32_16x16x32_bf16(a0, bh, acc[0][nf], 0, 0, 0);
      acc[1][nf] = __builtin_amdgcn_mfma_f32_16x16x32_bf16(a1, bh, acc[1][nf], 0, 0, 0);
      acc[0][nf] = __builtin_amdgcn_mfma_f32_16x16x32_bf16(a0, bl, acc[0][nf], 0, 0, 0);
      acc[1][nf] = __builtin_amdgcn_mfma_f32_16x16x32_bf16(a1, bl, acc[1][nf], 0, 0, 0);
    }
  }
  __builtin_amdgcn_s_setprio(0);

  // ---- epilogue: acc -> LDS bounce; stats partials ----
  float mrow[2][4];
#pragma unroll
  for (int mf = 0; mf < 2; ++mf)
#pragma unroll
    for (int rr = 0; rr < 4; ++rr) {
      const int row = rowBase + w * 32 + mf * 16 + lg * 4 + rr;
      float m = 0.f;
      if (row < nrows) m = MASKED ? ((tmask[row] > 0) ? 1.f : 0.f) : 1.f;
      mrow[mf][rr] = m;
    }
  __syncthreads();  // all waves done reading B
  ushort* Cs = SB;                      // [128][72]
  float* Sred = (float*)(SB + 9216);    // [4][64]
  float* Sq = Sred + 256;               // [4][64]
#pragma unroll
  for (int nf = 0; nf < 4; ++nf) {
    const int col = nf * 16 + lr;
    const float bcol = bias[cBase + col];
    float ps = 0.f, pq = 0.f;
#pragma unroll
    for (int mf = 0; mf < 2; ++mf) {
      const f32x4 vv = acc[mf][nf];
#pragma unroll
      for (int rr = 0; rr < 4; ++rr) {
        const float o = vv[rr] + bcol;
        const int rl = w * 32 + mf * 16 + lg * 4 + rr;
        Cs[rl * 72 + col] = bf_hi(o);
        const float mo = mrow[mf][rr] * o;
        ps += mo;
        pq += mo * o;
      }
    }
    ps += __shfl_xor(ps, 16);
    ps += __shfl_xor(ps, 32);
    pq += __shfl_xor(pq, 16);
    pq += __shfl_xor(pq, 32);
    if (lg == 0) {
      Sred[w * 64 + col] = ps;
      Sq[w * 64 + col] = pq;
    }
  }
  __syncthreads();
  {
    const int rl = tid >> 1, half = tid & 1;
    const int grow = rowBase + rl;
    if (grow < nrows) {
      ushort* dstp = C + (size_t)grow * 128 + cBase + half * 32;
      const ushort* srcp = Cs + rl * 72 + half * 32;
#pragma unroll
      for (int j = 0; j < 4; ++j)
        *(short8v*)(dstp + j * 8) = *(const short8v*)(srcp + j * 8);
    }
  }
  if (tid < 64) {
    float s = 0.f;
#pragma unroll
    for (int q = 0; q < 4; ++q) s += Sred[q * 64 + tid];
    atomicAdd(&statsOut[rep * 512 + cBase + tid], s);
  } else if (tid < 128) {
    float s = 0.f;
#pragma unroll
    for (int q = 0; q < 4; ++q) s += Sq[q * 64 + tid - 64];
    atomicAdd(&statsOut[rep * 512 + 256 + cBase + tid - 64], s);
  }
}

// ---------------------------------------------------------------------------
// FUSED agg+GEMM1, FULL-WIDTH tile (128 rows x 128 cols, grid 782):
// each row's edges gathered exactly once (no column-split duplication).
// B hi/lo = 64KB LDS; launch_bounds(256,2).
// ---------------------------------------------------------------------------
__global__ __launch_bounds__(256, 2) void gemm_agg(
    const ushort* __restrict__ x, const ushort* __restrict__ feat,
    const int* __restrict__ offs, const int2* __restrict__ pairs,
    const float* __restrict__ deps, int layer, const ushort* __restrict__ WTh,
    const ushort* __restrict__ WTl, const float* __restrict__ bias,
    ushort* __restrict__ C, float* __restrict__ statsOut,
    int* __restrict__ tmask, int nrows) {
  __shared__ ushort SB[32768];  // Bh[16384] | Bl[16384]; reuse: Cs[128][136]+red
  ushort* Bh = SB;
  ushort* Bl = SB + 16384;
  const int tid = threadIdx.x;
  const int w = tid >> 6, lane = tid & 63, lr = lane & 15, lg = lane >> 4;
  const int rowBase = blockIdx.x * 128;
  const int rep = blockIdx.x & (NREP - 1);

  // ---- stage B once (128 cols x 128 k, swizzled) ----
  {
    const int cc = tid >> 1;       // col
    const int half = tid & 1;      // k half
    const ushort* sH = WTh + (size_t)cc * 128 + half * 64;
    const ushort* sL = WTl + (size_t)cc * 128 + half * 64;
    char* BhB = (char*)Bh;
    char* BlB = (char*)Bl;
#pragma unroll
    for (int i = 0; i < 8; ++i) {
      const int slot = half * 8 + i;
      const int off = (cc * 256 + slot * 16) ^ ((cc & 7) << 4);
      *(short8v*)(BhB + off) = *(const short8v*)(sH + i * 8);
      *(short8v*)(BlB + off) = *(const short8v*)(sL + i * 8);
    }
  }

  const float ce = 1.f + deps[layer];
  const int row0 = rowBase + w * 32 + lr;
  const int row1 = row0 + 16;
  int o0a = 0, o1a = 0, o0b = 0, o1b = 0;
  if (row0 < nrows) {
    o0a = offs[layer * Nn + row0];
    o1a = offs[layer * Nn + row0 + 1];
  }
  if (row1 < nrows) {
    o0b = offs[layer * Nn + row1];
    o1b = offs[layer * Nn + row1 + 1];
  }
  if (lg == 0) {
    if (row0 < nrows) tmask[row0] = (o1a > o0a) ? 1 : 0;
    if (row1 < nrows) tmask[row1] = (o1b > o0b) ? 1 : 0;
  }

  short8v ar0[4], ar1[4];
  // row0 fragments: one edge pass gathers full k-range (cols lg*8+c*32)
  {
    float a[4][8];
#pragma unroll
    for (int c = 0; c < 4; ++c)
#pragma unroll
      for (int j = 0; j < 8; ++j) a[c][j] = 0.f;
    for (int p = o0a; p < o1a; ++p) {
      const int2 pr = pairs[p];
      const float wgt = __int_as_float(pr.y);
      const ushort* xr = x + (size_t)pr.x * 128 + lg * 8;
#pragma unroll
      for (int c = 0; c < 4; ++c) {
        const short8v xv = *(const short8v*)(xr + c * 32);
#pragma unroll
        for (int j = 0; j < 8; ++j)
          a[c][j] = fmaf(wgt, bf_f((ushort)xv[j]), a[c][j]);
      }
    }
    if (o1a > o0a) {
      const ushort* fr = feat + (size_t)row0 * 128 + lg * 8;
#pragma unroll
      for (int c = 0; c < 4; ++c) {
        const short8v fv = *(const short8v*)(fr + c * 32);
#pragma unroll
        for (int j = 0; j < 8; ++j)
          a[c][j] = fmaf(ce, bf_f((ushort)fv[j]), a[c][j]);
      }
    }
#pragma unroll
    for (int c = 0; c < 4; ++c)
#pragma unroll
      for (int j = 0; j < 8; ++j) ar0[c][j] = (short)bf_hi(a[c][j]);
  }
  // row1 fragments
  {
    float a[4][8];
#pragma unroll
    for (int c = 0; c < 4; ++c)
#pragma unroll
      for (int j = 0; j < 8; ++j) a[c][j] = 0.f;
    for (int p = o0b; p < o1b; ++p) {
      const int2 pr = pairs[p];
      const float wgt = __int_as_float(pr.y);
      const ushort* xr = x + (size_t)pr.x * 128 + lg * 8;
#pragma unroll
      for (int c = 0; c < 4; ++c) {
        const short8v xv = *(const short8v*)(xr + c * 32);
#pragma unroll
        for (int j = 0; j < 8; ++j)
          a[c][j] = fmaf(wgt, bf_f((ushort)xv[j]), a[c][j]);
      }
    }
    if (o1b > o0b) {
      const ushort* fr = feat + (size_t)row1 * 128 + lg * 8;
#pragma unroll
      for (int c = 0; c < 4; ++c) {
        const short8v fv = *(const short8v*)(fr + c * 32);
#pragma unroll
        for (int j = 0; j < 8; ++j)
          a[c][j] = fmaf(ce, bf_f((ushort)fv[j]), a[c][j]);
      }
    }
#pragma unroll
    for (int c = 0; c < 4; ++c)
#pragma unroll
      for (int j = 0; j < 8; ++j) ar1[c][j] = (short)bf_hi(a[c][j]);
  }
  __syncthreads();

  const f32x4 fzero = {0.f, 0.f, 0.f, 0.f};
  f32x4 acc[2][8];
#pragma unroll
  for (int i = 0; i < 2; ++i)
#pragma unroll
    for (int j = 0; j < 8; ++j) acc[i][j] = fzero;

  const char* BhB = (const char*)Bh;
  const char* BlB = (const char*)Bl;
  __builtin_amdgcn_s_setprio(1);
#pragma unroll
  for (int c = 0; c < 4; ++c) {
    const short8v a0 = ar0[c], a1 = ar1[c];
#pragma unroll
    for (int nf = 0; nf < 8; ++nf) {
      const int brow = nf * 16 + lr;
      const int off = (brow * 256 + (c * 4 + lg) * 16) ^ ((lr & 7) << 4);
      const short8v bh = *(const short8v*)(BhB + off);
      const short8v bl = *(const short8v*)(BlB + off);
      acc[0][nf] = __builtin_amdgcn_mfma_f32_16x16x32_bf16(a0, bh, acc[0][nf], 0, 0, 0);
      acc[1][nf] = __builtin_amdgcn_mfma_f32_16x16x32_bf16(a1, bh, acc[1][nf], 0, 0, 0);
      acc[0][nf] = __builtin_amdgcn_mfma_f32_16x16x32_bf16(a0, bl, acc[0][nf], 0, 0, 0);
      acc[1][nf] = __builtin_amdgcn_mfma_f32_16x16x32_bf16(a1, bl, acc[1][nf], 0, 0, 0);
    }
  }
  __builtin_amdgcn_s_setprio(0);

  // ---- epilogue: mask via shfl of per-row deg flags ----
  const float dga = (o1a > o0a) ? 1.f : 0.f;
  const float dgb = (o1b > o0b) ? 1.f : 0.f;
  float mrow[2][4];
#pragma unroll
  for (int rr = 0; rr < 4; ++rr) {
    const int srcl = lg * 4 + rr;  // lane holding that row's deg flag
    mrow[0][rr] = __shfl(dga, srcl, 64);
    mrow[1][rr] = __shfl(dgb, srcl, 64);
  }
#pragma unroll
  for (int mf = 0; mf < 2; ++mf)
#pragma unroll
    for (int rr = 0; rr < 4; ++rr) {
      const int row = rowBase + w * 32 + mf * 16 + lg * 4 + rr;
      if (row >= nrows) mrow[mf][rr] = 0.f;
    }
  __syncthreads();
  ushort* Cs = SB;                     // [128][136]
  float* Sred = (float*)(SB + 17408);  // [4][128]
  float* Sq = Sred + 512;              // [4][128]
#pragma unroll
  for (int nf = 0; nf < 8; ++nf) {
    const int col = nf * 16 + lr;
    const float bcol = bias[col];
    float ps = 0.f, pq = 0.f;
#pragma unroll
    for (int mf = 0; mf < 2; ++mf) {
      const f32x4 vv = acc[mf][nf];
#pragma unroll
      for (int rr = 0; rr < 4; ++rr) {
        const float o = vv[rr] + bcol;
        const int rl = w * 32 + mf * 16 + lg * 4 + rr;
        Cs[rl * 136 + col] = bf_hi(o);
        const float mo = mrow[mf][rr] * o;
        ps += mo;
        pq += mo * o;
      }
    }
    ps += __shfl_xor(ps, 16);
    ps += __shfl_xor(ps, 32);
    pq += __shfl_xor(pq, 16);
    pq += __shfl_xor(pq, 32);
    if (lg == 0) {
      Sred[w * 128 + col] = ps;
      Sq[w * 128 + col] = pq;
    }
  }
  __syncthreads();
  {
    const int rl = tid >> 1, half = tid & 1;
    const int grow = rowBase + rl;
    if (grow < nrows) {
      ushort* dstp = C + (size_t)grow * 128 + half * 64;
      const ushort* srcp = Cs + rl * 136 + half * 64;
#pragma unroll
      for (int j = 0; j < 8; ++j)
        *(short8v*)(dstp + j * 8) = *(const short8v*)(srcp + j * 8);
    }
  }
  {
    const int col = tid & 127;
    float s = 0.f;
    if (tid < 128) {
#pragma unroll
      for (int q = 0; q < 4; ++q) s += Sred[q * 128 + col];
      atomicAdd(&statsOut[rep * 512 + col], s);
    } else {
#pragma unroll
      for (int q = 0; q < 4; ++q) s += Sq[q * 128 + col];
      atomicAdd(&statsOut[rep * 512 + 256 + col], s);
    }
  }
}

// ---------------------------------------------------------------------------
// GEMM #1: fp32 A (dag_x), K=64, hi/lo-split A (3 MFMAs). Same epilogue.
// ---------------------------------------------------------------------------
__global__ __launch_bounds__(256, 4) void gemm_f32a(
    const float* __restrict__ A, const ushort* __restrict__ WTh,
    const ushort* __restrict__ WTl, const float* __restrict__ bias,
    ushort* __restrict__ C, float* __restrict__ statsOut, int nrows) {
  __shared__ ushort SB[11264];  // Bh[4096] | Bl[4096]; reused Cs[128][72]+red
  ushort* Bh = SB;
  ushort* Bl = SB + 4096;
  const int tid = threadIdx.x;
  const int w = tid >> 6, lane = tid & 63, lr = lane & 15, lg = lane >> 4;
  const int rt = blockIdx.x >> 1, ct = blockIdx.x & 1;
  const int rowBase = rt * 128, cBase = ct * 64;
  const int rep = blockIdx.x & (NREP - 1);

  {
    const int cc = tid >> 2;
    const ushort* sH = WTh + (size_t)(cBase + cc) * 64;
    const ushort* sL = WTl + (size_t)(cBase + cc) * 64;
    char* BhB = (char*)Bh;
    char* BlB = (char*)Bl;
#pragma unroll
    for (int i = 0; i < 2; ++i) {
      const int slot = (tid & 3) * 2 + i;
      const int off = (cc * 128 + slot * 16) ^ ((cc & 7) << 4);
      *(short8v*)(BhB + off) = *(const short8v*)(sH + slot * 8);
      *(short8v*)(BlB + off) = *(const short8v*)(sL + slot * 8);
    }
  }

  const int row0 = rowBase + w * 32 + lr;
  const int row1 = row0 + 16;
  const bool ok0 = row0 < nrows, ok1 = row1 < nrows;
  const float4 fz4 = make_float4(0.f, 0.f, 0.f, 0.f);
  const float* aP0 = A + (size_t)row0 * 64 + lg * 8;
  const float* aP1 = A + (size_t)row1 * 64 + lg * 8;
  float4 ar0[2][2], ar1[2][2];
#pragma unroll
  for (int c = 0; c < 2; ++c) {
    ar0[c][0] = ok0 ? *(const float4*)(aP0 + c * 32) : fz4;
    ar0[c][1] = ok0 ? *(const float4*)(aP0 + c * 32 + 4) : fz4;
    ar1[c][0] = ok1 ? *(const float4*)(aP1 + c * 32) : fz4;
    ar1[c][1] = ok1 ? *(const float4*)(aP1 + c * 32 + 4) : fz4;
  }
  __syncthreads();

  const f32x4 fzero = {0.f, 0.f, 0.f, 0.f};
  f32x4 acc[2][4];
#pragma unroll
  for (int i = 0; i < 2; ++i)
#pragma unroll
    for (int j = 0; j < 4; ++j) acc[i][j] = fzero;

  const char* BhB = (const char*)Bh;
  const char* BlB = (const char*)Bl;
  __builtin_amdgcn_s_setprio(1);
#pragma unroll
  for (int c = 0; c < 2; ++c) {
    const float v0[8] = {ar0[c][0].x, ar0[c][0].y, ar0[c][0].z, ar0[c][0].w,
                         ar0[c][1].x, ar0[c][1].y, ar0[c][1].z, ar0[c][1].w};
    const float v1[8] = {ar1[c][0].x, ar1[c][0].y, ar1[c][0].z, ar1[c][0].w,
                         ar1[c][1].x, ar1[c][1].y, ar1[c][1].z, ar1[c][1].w};
    short8v a0h, a0l, a1h, a1l;
#pragma unroll
    for (int j = 0; j < 8; ++j) {
      ushort hh = bf_hi(v0[j]);
      a0h[j] = (short)hh;
      a0l[j] = (short)bf_hi(v0[j] - bf_f(hh));
      hh = bf_hi(v1[j]);
      a1h[j] = (short)hh;
      a1l[j] = (short)bf_hi(v1[j] - bf_f(hh));
    }
#pragma unroll
    for (int nf = 0; nf < 4; ++nf) {
      const int brow = nf * 16 + lr;
      const int off = (brow * 128 + (c * 4 + lg) * 16) ^ ((lr & 7) << 4);
      const short8v bh = *(const short8v*)(BhB + off);
      const short8v bl = *(const short8v*)(BlB + off);
      acc[0][nf] = __builtin_amdgcn_mfma_f32_16x16x32_bf16(a0h, bh, acc[0][nf], 0, 0, 0);
      acc[1][nf] = __builtin_amdgcn_mfma_f32_16x16x32_bf16(a1h, bh, acc[1][nf], 0, 0, 0);
      acc[0][nf] = __builtin_amdgcn_mfma_f32_16x16x32_bf16(a0l, bh, acc[0][nf], 0, 0, 0);
      acc[1][nf] = __builtin_amdgcn_mfma_f32_16x16x32_bf16(a1l, bh, acc[1][nf], 0, 0, 0);
      acc[0][nf] = __builtin_amdgcn_mfma_f32_16x16x32_bf16(a0h, bl, acc[0][nf], 0, 0, 0);
      acc[1][nf] = __builtin_amdgcn_mfma_f32_16x16x32_bf16(a1h, bl, acc[1][nf], 0, 0, 0);
    }
  }
  __builtin_amdgcn_s_setprio(0);

  __syncthreads();
  ushort* Cs = SB;                    // [128][72]
  float* Sred = (float*)(SB + 9216);  // [4][64]
  float* Sq = Sred + 256;
#pragma unroll
  for (int nf = 0; nf < 4; ++nf) {
    const int col = nf * 16 + lr;
    const float bcol = bias[cBase + col];
    float ps = 0.f, pq = 0.f;
#pragma unroll
    for (int mf = 0; mf < 2; ++mf) {
      const f32x4 vv = acc[mf][nf];
#pragma unroll
      for (int rr = 0; rr < 4; ++rr) {
        const float o = vv[rr] + bcol;
        const int rl = w * 32 + mf * 16 + lg * 4 + rr;
        Cs[rl * 72 + col] = bf_hi(o);
        const int row = rowBase + rl;
        const float m = (row < nrows) ? 1.f : 0.f;
        const float mo = m * o;
        ps += mo;
        pq += mo * o;
      }
    }
    ps += __shfl_xor(ps, 16);
    ps += __shfl_xor(ps, 32);
    pq += __shfl_xor(pq, 16);
    pq += __shfl_xor(pq, 32);
    if (lg == 0) {
      Sred[w * 64 + col] = ps;
      Sq[w * 64 + col] = pq;
    }
  }
  __syncthreads();
  {
    const int rl = tid >> 1, half = tid & 1;
    const int grow = rowBase + rl;
    if (grow < nrows) {
      ushort* dstp = C + (size_t)grow * 128 + cBase + half * 32;
      const ushort* srcp = Cs + rl * 72 + half * 32;
#pragma unroll
      for (int j = 0; j < 4; ++j)
        *(short8v*)(dstp + j * 8) = *(const short8v*)(srcp + j * 8);
    }
  }
  if (tid < 64) {
    float s = 0.f;
#pragma unroll
    for (int q = 0; q < 4; ++q) s += Sred[q * 64 + tid];
    atomicAdd(&statsOut[rep * 512 + cBase + tid], s);
  } else if (tid < 128) {
    float s = 0.f;
#pragma unroll
    for (int q = 0; q < 4; ++q) s += Sq[q * 64 + tid - 64];
    atomicAdd(&statsOut[rep * 512 + 256 + cBase + tid - 64], s);
  }
}

// Weight transpose + hi/lo split: 8 slots of 32768 ushorts (hi, lo@+16384)
__global__ __launch_bounds__(256) void wsplit_kernel(
    const float* __restrict__ W1, const float* __restrict__ W2,
    const float* __restrict__ dW1, const float* __restrict__ dW2,
    ushort* __restrict__ wsT) {
  const int t = blockIdx.x * 256 + threadIdx.x;
  const int slot = t >> 14;
  const int idx = t & 16383;
  if (slot >= 8) return;
  const int Ks = (slot == 0) ? 64 : 128;
  if (idx >= 128 * Ks) return;
  const int c = idx / Ks;
  const int k = idx - c * Ks;
  float v;
  if (slot == 0) v = W1[k * 128 + c];
  else if (slot == 1) v = W2[k * 128 + c];
  else if (slot < 5) v = dW1[(slot - 2) * 16384 + k * 128 + c];
  else v = dW2[(slot - 5) * 16384 + k * 128 + c];
  const ushort h = bf_hi(v);
  const ushort l = bf_hi(v - bf_f(h));
  wsT[slot * 32768 + c * Ks + k] = h;
  wsT[slot * 32768 + 16384 + c * Ks + k] = l;
}

// feat = relu(y*sc+sh); also zeroes x (replaces the xbuf memset dispatch).
__global__ __launch_bounds__(256) void normrelu_kernel(
    const ushort* __restrict__ in, const float* __restrict__ stats,
    const float* __restrict__ g, const float* __restrict__ be, float cntFixed,
    ushort* __restrict__ outp, ushort* __restrict__ xz) {
  __shared__ float ssS[256];
  compute_ss_lds(stats, g, be, cntFixed, ssS);
  __syncthreads();
  const int tid = threadIdx.x;
  const int c4 = (tid & 31) * 4;
  const float4 sc = *(const float4*)&ssS[c4];
  const float4 sh = *(const float4*)&ssS[128 + c4];
  const int rowBase = blockIdx.x * 64;
  const ushort4 z4 = make_ushort4(0, 0, 0, 0);
#pragma unroll
  for (int it = 0; it < 8; ++it) {
    const int row = rowBase + it * 8 + (tid >> 5);
    if (row >= Nn) continue;
    const size_t idx = (size_t)row * 32 + (tid & 31);
    const ushort4 v = ((const ushort4*)in)[idx];
    ushort4 o;
    o.x = bf_hi(fmaxf(fmaf(bf_f(v.x), sc.x, sh.x), 0.f));
    o.y = bf_hi(fmaxf(fmaf(bf_f(v.y), sc.y, sh.y), 0.f));
    o.z = bf_hi(fmaxf(fmaf(bf_f(v.z), sc.z, sh.z), 0.f));
    o.w = bf_hi(fmaxf(fmaf(bf_f(v.w), sc.w, sh.w), 0.f));
    ((ushort4*)outp)[idx] = o;
    ((ushort4*)xz)[idx] = z4;
  }
}

// x += (tmask>0) * relu(y*sc+sh)
__global__ __launch_bounds__(256) void normrelu_acc_kernel(
    const ushort* __restrict__ in, const float* __restrict__ stats,
    const float* __restrict__ g, const float* __restrict__ be,
    const float* __restrict__ cntPtr, const int* __restrict__ tmask,
    ushort* __restrict__ x) {
  __shared__ float ssS[256];
  compute_ss_lds(stats, g, be, fmaxf(cntPtr[0], 1.f), ssS);
  __syncthreads();
  const int tid = threadIdx.x;
  const int c4 = (tid & 31) * 4;
  const float4 sc = *(const float4*)&ssS[c4];
  const float4 sh = *(const float4*)&ssS[128 + c4];
  const int rowBase = blockIdx.x * 64;
#pragma unroll
  for (int it = 0; it < 8; ++it) {
    const int row = rowBase + it * 8 + (tid >> 5);
    if (row >= Nn || tmask[row] <= 0) continue;
    const size_t idx = (size_t)row * 32 + (tid & 31);
    const ushort4 v = ((const ushort4*)in)[idx];
    ushort4 xo = ((const ushort4*)x)[idx];
    xo.x = bf_hi(bf_f(xo.x) + fmaxf(fmaf(bf_f(v.x), sc.x, sh.x), 0.f));
    xo.y = bf_hi(bf_f(xo.y) + fmaxf(fmaf(bf_f(v.y), sc.y, sh.y), 0.f));
    xo.z = bf_hi(bf_f(xo.z) + fmaxf(fmaf(bf_f(v.z), sc.z, sh.z), 0.f));
    xo.w = bf_hi(bf_f(xo.w) + fmaxf(fmaf(bf_f(v.w), sc.w, sh.w), 0.f));
    ((ushort4*)x)[idx] = xo;
  }
}

__global__ __launch_bounds__(256) void scatter_leaves_kernel(
    const int* __restrict__ leaves, const ushort* __restrict__ feat,
    ushort* __restrict__ x, int nl) {
  const int gid = blockIdx.x * 256 + threadIdx.x;
  const int j = gid >> 5;
  if (j >= nl) return;
  const int node = leaves[j];
  const int c4 = (gid & 31) * 4;
  *(ushort4*)&x[(size_t)node * 128 + c4] =
      *(const ushort4*)&feat[(size_t)node * 128 + c4];
}

// ---------------- CSR build ----------------
__global__ __launch_bounds__(256) void deg_count_kernel(
    const int* __restrict__ dst, const int* __restrict__ lmask,
    int* __restrict__ cnts) {
  const int e = blockIdx.x * 256 + threadIdx.x;
  if (e >= Ee) return;
  atomicAdd(&cnts[lmask[e] * Nn + dst[e]], 1);
}

// scan1 + fused per-layer target count (nodes with deg>0) -> tcountf[0..2]
__global__ __launch_bounds__(256) void scan1_kernel(const int* __restrict__ in,
                                                    int* __restrict__ out,
                                                    int* __restrict__ bsum,
                                                    float* __restrict__ tcountf,
                                                    int n) {
  __shared__ int lds[256];
  __shared__ float tcS[3];
  const int tid = threadIdx.x;
  const int base = blockIdx.x * 2048 + tid * 8;
  int vals[8];
  int tsum = 0;
  float t0 = 0.f, t1 = 0.f, t2 = 0.f;
#pragma unroll
  for (int j = 0; j < 8; ++j) {
    const int i = base + j;
    const int v = (i < n) ? in[i] : 0;
    if (v > 0) {
      if (i < Nn) t0 += 1.f;
      else if (i < 2 * Nn) t1 += 1.f;
      else t2 += 1.f;
    }
    vals[j] = tsum;
    tsum += v;
  }
  lds[tid] = tsum;
  if (tid < 3) tcS[tid] = 0.f;
  __syncthreads();
  if (t0 != 0.f) atomicAdd(&tcS[0], t0);
  if (t1 != 0.f) atomicAdd(&tcS[1], t1);
  if (t2 != 0.f) atomicAdd(&tcS[2], t2);
  for (int off = 1; off < 256; off <<= 1) {
    const int y = (tid >= off) ? lds[tid - off] : 0;
    __syncthreads();
    lds[tid] += y;
    __syncthreads();
  }
  const int texcl = (tid > 0) ? lds[tid - 1] : 0;
#pragma unroll
  for (int j = 0; j < 8; ++j)
    if (base + j < n) out[base + j] = texcl + vals[j];
  if (tid == 255) bsum[blockIdx.x] = lds[255];
  __syncthreads();
  if (tid < 3 && tcS[tid] != 0.f) atomicAdd(&tcountf[tid], tcS[tid]);
}

// scan3 with scan2 fused: each block redundantly scans the 147 block sums.
__global__ __launch_bounds__(256) void scan3_kernel(int* __restrict__ out,
                                                    int* __restrict__ cursor,
                                                    const int* __restrict__ bsum,
                                                    int nb, int n, int etot) {
  __shared__ int bs[256];
  const int tid = threadIdx.x;
  const int v = (tid < nb) ? bsum[tid] : 0;
  bs[tid] = v;
  __syncthreads();
  for (int off = 1; off < 256; off <<= 1) {
    const int y = (tid >= off) ? bs[tid - off] : 0;
    __syncthreads();
    bs[tid] += y;
    __syncthreads();
  }
  const int i = blockIdx.x * 256 + tid;
  if (i >= n) return;
  const int b = i >> 11;
  const int excl = (b > 0) ? bs[b - 1] : 0;
  const int val = out[i] + excl;
  out[i] = val;
  cursor[i] = val;
  if (i == n - 1) out[n] = etot;
}

__global__ __launch_bounds__(256) void csr_fill_kernel(
    const int* __restrict__ src, const int* __restrict__ dst,
    const float* __restrict__ mult, const int* __restrict__ lmask,
    int* __restrict__ cursor, int2* __restrict__ pairs) {
  const int e = blockIdx.x * 256 + threadIdx.x;
  if (e >= Ee) return;
  const int slot = atomicAdd(&cursor[lmask[e] * Nn + dst[e]], 1);
  pairs[slot] = make_int2(src[e], __float_as_int(mult[e]));
}

// ---------------- readout: replicated-bucket counting-sort pool -----------
__global__ __launch_bounds__(256) void phist_kernel(const int* __restrict__ ridx,
                                                    const int* __restrict__ batch,
                                                    int* __restrict__ cnt, int n) {
  const int i = blockIdx.x * 256 + threadIdx.x;
  if (i >= n) return;
  atomicAdd(&cnt[batch[ridx[i]] * PR + (i & (PR - 1))], 1);
}

// exclusive scan over 256*PR = 8192 buckets (single block, 32 elems/thread)
__global__ void pscan_kernel(int* __restrict__ cnt, int* __restrict__ cur) {
  __shared__ int l[256];
  const int t = threadIdx.x;
  const int base = t * 32;
  int vals[32];
  int tsum = 0;
#pragma unroll
  for (int j = 0; j < 32; ++j) {
    const int v = cnt[base + j];
    vals[j] = tsum;
    tsum += v;
  }
  l[t] = tsum;
  __syncthreads();
  for (int off = 1; off < 256; off <<= 1) {
    const int y = (t >= off) ? l[t - off] : 0;
    __syncthreads();
    l[t] += y;
    __syncthreads();
  }
  const int excl = (t > 0) ? l[t - 1] : 0;
#pragma unroll
  for (int j = 0; j < 32; ++j) {
    const int v = excl + vals[j];
    cnt[base + j] = v;
    cur[base + j] = v;
  }
}

__global__ __launch_bounds__(256) void pfill_kernel(const int* __restrict__ ridx,
                                                    const int* __restrict__ batch,
                                                    int* __restrict__ cur,
                                                    int* __restrict__ sorted,
                                                    int n) {
  const int i = blockIdx.x * 256 + threadIdx.x;
  if (i >= n) return;
  const int node = ridx[i];
  const int slot = atomicAdd(&cur[batch[node] * PR + (i & (PR - 1))], 1);
  sorted[slot] = node;
}

// Parallel pool: 8 slices per graph -> Ppart[g*8+slice][128] (no atomics)
__global__ __launch_bounds__(256) void ppool_kernel(const int* __restrict__ sorted,
                                                    const int* __restrict__ offs,
                                                    const ushort* __restrict__ x,
                                                    float* __restrict__ Ppart,
                                                    int n) {
  __shared__ float part[4][256];
  const int bid = blockIdx.x;
  const int g = bid >> 3, slice = bid & (PSL - 1);
  const int w = threadIdx.x >> 6;
  const int lane = threadIdx.x & 63;
  const int o0 = offs[g * PR];
  const int o1 = (g < Gg - 1) ? offs[(g + 1) * PR] : n;
  float ax = 0.f, ay = 0.f;
  for (int p = o0 + slice * 4 + w; p < o1; p += 32) {
    const int node = sorted[p];
    const ushort2 xv = *(const ushort2*)&x[(size_t)node * 128 + lane * 2];
    ax += bf_f(xv.x);
    ay += bf_f(xv.y);
  }
  part[w][lane * 2] = ax;
  part[w][lane * 2 + 1] = ay;
  __syncthreads();
  if (threadIdx.x < 128) {
    const int c = threadIdx.x;
    Ppart[(size_t)bid * 128 + c] =
        part[0][c] + part[1][c] + part[2][c] + part[3][c];
  }
}

// Fused preduce + final linear: out[g][t] = 0.25*sum_slices(Ppart)@Wl + bl
__global__ __launch_bounds__(128) void pout_kernel(
    const float* __restrict__ Ppart, const float* __restrict__ Wl,
    const float* __restrict__ bl, float* __restrict__ out) {
  __shared__ float Pl[128];
  const int g = blockIdx.x;
  const int t = threadIdx.x;  // 128
  float s = 0.f;
#pragma unroll
  for (int r = 0; r < PSL; ++r) s += Ppart[(size_t)(g * PSL + r) * 128 + t];
  Pl[t] = s * 0.25f;
  __syncthreads();
  if (t < Tt) {
    float acc = 0.f;
    for (int c = 0; c < 128; ++c) acc += Pl[c] * Wl[c * Tt + t];
    out[g * Tt + t] = acc + bl[t];
  }
}

extern "C" void kernel_launch(void* const* d_in, const int* in_sizes, int n_in,
                              void* d_out, int out_size, void* d_ws,
                              size_t ws_size, hipStream_t stream) {
  const float* dag_x = (const float*)d_in[0];
  const int* eidx = (const int*)d_in[1];
  const int* src = eidx;
  const int* dst = eidx + Ee;
  const float* mult = (const float*)d_in[2];
  const int* lmask = (const int*)d_in[3];
  const int* batch = (const int*)d_in[4];
  const int* leaves = (const int*)d_in[5];
  const int* readouts = (const int*)d_in[6];
  const float* W1 = (const float*)d_in[7];
  const float* b1 = (const float*)d_in[8];
  const float* g1 = (const float*)d_in[9];
  const float* be1 = (const float*)d_in[10];
  const float* W2 = (const float*)d_in[11];
  const float* b2 = (const float*)d_in[12];
  const float* g2 = (const float*)d_in[13];
  const float* be2 = (const float*)d_in[14];
  const float* dW1 = (const float*)d_in[15];
  const float* db1 = (const float*)d_in[16];
  const float* dg1 = (const float*)d_in[17];
  const float* dbe1 = (const float*)d_in[18];
  const float* dW2 = (const float*)d_in[19];
  const float* db2 = (const float*)d_in[20];
  const float* dg2 = (const float*)d_in[21];
  const float* dbe2 = (const float*)d_in[22];
  const float* deps = (const float*)d_in[23];
  const float* Wl = (const float*)d_in[24];
  const float* bl = (const float*)d_in[25];
  float* out = (float*)d_out;

  const size_t ND = (size_t)Nn * Dd;
  ushort* feat = (ushort*)d_ws;           // ND bf16
  ushort* xbuf = feat + ND;               // ND bf16
  ushort* Abuf = xbuf + ND;               // ND bf16
  ushort* Bbuf = Abuf + ND;               // ND bf16 (gemm ping-pong)
  float* statsAll = (float*)(Bbuf + ND);  // 8 slots x [16][512]
  float* tcountf = statsAll + 8 * 8192;   // 8 (4 used) -- adjacent for memset
  int* tmask = (int*)(tcountf + 8);       // N
  ushort* wsT = (ushort*)(tmask + Nn);    // 262144 (8 weight slots, hi+lo)
  int* offs = (int*)(wsT + 262144);       // 3N+4
  int2* pairs = (int2*)(offs + 3 * Nn + 4);  // E pairs (src, mult)

  // transient overlays (xbuf region before it's initialized):
  int* cnts = (int*)xbuf;                 // 3N
  int* cursor = cnts + 3 * Nn;            // 3N
  int* bsum = cursor + 3 * Nn;            // 147
  const int nridx = in_sizes[6];          // 80000
  const int nleaves = in_sizes[5];        // 50000
  // pool overlays (Abuf dead by readout):
  int* pcnt = (int*)Abuf;                 // 256*PR (becomes offsets)
  int* pcur = pcnt + Gg * PR;             // 256*PR
  int* sorted = pcur + Gg * PR;           // nridx
  float* Ppart = (float*)(sorted + nridx);  // 2048*128

  dim3 blk(256);
  hipMemsetAsync(statsAll, 0, (8 * 8192 + 8) * sizeof(float), stream);
  wsplit_kernel<<<512, blk, 0, stream>>>(W1, W2, dW1, dW2, wsT);

  // ---- CSR build (tcount fused into scan1; scan2 fused into scan3) ----
  hipMemsetAsync(cnts, 0, 3 * Nn * sizeof(int), stream);
  deg_count_kernel<<<2344, blk, 0, stream>>>(dst, lmask, cnts);
  scan1_kernel<<<147, blk, 0, stream>>>(cnts, offs, bsum, tcountf, 3 * Nn);
  scan3_kernel<<<1172, blk, 0, stream>>>(offs, cursor, bsum, 147, 3 * Nn, Ee);
  csr_fill_kernel<<<2344, blk, 0, stream>>>(src, dst, mult, lmask, cursor, pairs);

  const int gGemm = 782 * 2;
  // ---- node feature transform ----
  gemm_f32a<<<gGemm, blk, 0, stream>>>(dag_x, wsT, wsT + 16384, b1, Abuf,
                                       statsAll + 0 * 8192, Nn);
  gemm_bf16<true, false><<<gGemm, blk, 0, stream>>>(
      Abuf, wsT + 32768, wsT + 32768 + 16384, b2, statsAll + 0 * 8192, g1, be1,
      nullptr, nullptr, Bbuf, statsAll + 1 * 8192, Nn);
  // feat = relu(bn(y2)); also zeroes xbuf (no memset dispatch)
  normrelu_kernel<<<1563, blk, 0, stream>>>(Bbuf, statsAll + 1 * 8192, g2, be2,
                                            (float)Nn, feat, xbuf);
  scatter_leaves_kernel<<<6250, blk, 0, stream>>>(leaves, feat, xbuf, nleaves);

  // ---- DAG layers (agg fused into gemm1; full-width 128x128 tile) ----
  for (int layer = 0; layer < Ll; ++layer) {
    const int so1 = (2 + layer) * 32768;
    const int so2 = (5 + layer) * 32768;
    const int po = layer * Dd;
    float* st1 = statsAll + (size_t)(2 + 2 * layer) * 8192;
    float* st2 = statsAll + (size_t)(3 + 2 * layer) * 8192;
    gemm_agg<<<782, blk, 0, stream>>>(xbuf, feat, offs, pairs, deps, layer,
                                      wsT + so1, wsT + so1 + 16384, db1 + po,
                                      Bbuf, st1, tmask, Nn);
    gemm_bf16<true, true><<<gGemm, blk, 0, stream>>>(
        Bbuf, wsT + so2, wsT + so2 + 16384, db2 + po, st1, dg1 + po, dbe1 + po,
        tcountf + layer, tmask, Abuf, st2, Nn);
    normrelu_acc_kernel<<<1563, blk, 0, stream>>>(
        Abuf, st2, dg2 + po, dbe2 + po, tcountf + layer, tmask, xbuf);
  }

  // ---- readout (replicated-bucket counting sort, no float atomics) ----
  hipMemsetAsync(pcnt, 0, Gg * PR * sizeof(int), stream);
  const int gIdx = (nridx + 255) / 256;
  phist_kernel<<<gIdx, blk, 0, stream>>>(readouts, batch, pcnt, nridx);
  pscan_kernel<<<1, blk, 0, stream>>>(pcnt, pcur);
  pfill_kernel<<<gIdx, blk, 0, stream>>>(readouts, batch, pcur, sorted, nridx);
  ppool_kernel<<<Gg * PSL, blk, 0, stream>>>(sorted, pcnt, xbuf, Ppart, nridx);
  pout_kernel<<<Gg, dim3(128), 0, stream>>>(Ppart, Wl, bl, out);
}

// Round 14
// 412.170 us; speedup vs baseline: 1.2628x; 1.1165x over previous
//
#include <hip/hip_runtime.h>

constexpr int Nn = 100000;   // nodes
constexpr int Ee = 600000;   // edges
constexpr int Dd = 128;      // hidden dim
constexpr int Ll = 3;        // DAG layers
constexpr int Gg = 256;      // graphs
constexpr int Tt = 10;       // outputs per graph
constexpr float BN_EPS = 1e-5f;
constexpr int NREP = 16;     // stats replicas (slot = [16][512] floats)
constexpr int PSL = 8;       // pool slices per graph
constexpr int PR = 32;       // counting-sort bucket replicas per graph

typedef __attribute__((ext_vector_type(8))) short short8v;
typedef __attribute__((ext_vector_type(4))) float f32x4;

__device__ inline ushort bf_hi(float f) {
  unsigned u = __float_as_uint(f);
  unsigned r = (u + 0x7FFFu + ((u >> 16) & 1u)) >> 16;
  return (ushort)r;
}
__device__ inline float bf_f(ushort h) {
  return __uint_as_float(((unsigned)h) << 16);
}

// BN scale/shift from a replicated stats slot -> LDS ssS[256] (threads 0..127)
__device__ inline void compute_ss_lds(const float* __restrict__ stats,
                                      const float* __restrict__ g,
                                      const float* __restrict__ be, float cnt,
                                      float* ssS) {
  const int c = threadIdx.x;
  if (c < 128) {
    float S = 0.f, Q = 0.f;
#pragma unroll
    for (int r = 0; r < NREP; ++r) {
      S += stats[r * 512 + c];
      Q += stats[r * 512 + 256 + c];
    }
    const float m = S / cnt;
    const float v = Q / cnt - m * m;
    const float sc = g[c] * rsqrtf(v + BN_EPS);
    ssS[c] = sc;
    ssS[128 + c] = be[c] - m * sc;
  }
}

// ---------------------------------------------------------------------------
// B-resident barrier-free GEMM (bf16 A, single-bf16 B): 128 rows x 64 cols.
// ---------------------------------------------------------------------------
template <bool NORM_A, bool MASKED>
__global__ __launch_bounds__(256, 6) void gemm_bf16(
    const ushort* __restrict__ A, const ushort* __restrict__ WTh,
    const float* __restrict__ bias, const float* __restrict__ statsIn,
    const float* __restrict__ gN, const float* __restrict__ beN,
    const float* __restrict__ cntPtr, const int* __restrict__ tmask,
    ushort* __restrict__ C, float* __restrict__ statsOut, int nrows) {
  __shared__ ushort SB[10240];  // Bh[8192]; reused: Cs[128][72] + red[1024]
  __shared__ float ssS[256];
  ushort* Bh = SB;
  const int tid = threadIdx.x;
  const int w = tid >> 6, lane = tid & 63, lr = lane & 15, lg = lane >> 4;
  const int rt = blockIdx.x >> 1, ct = blockIdx.x & 1;
  const int rowBase = rt * 128, cBase = ct * 64;
  const int rep = blockIdx.x & (NREP - 1);

  // ---- stage B once (swizzle: byte ^= (col&7)<<4 within 256B row) ----
  {
    const int cc = tid >> 2;
    const ushort* sH = WTh + (size_t)(cBase + cc) * 128;
    char* BhB = (char*)Bh;
#pragma unroll
    for (int i = 0; i < 4; ++i) {
      const int slot = (tid & 3) * 4 + i;
      const int off = (cc * 256 + slot * 16) ^ ((cc & 7) << 4);
      *(short8v*)(BhB + off) = *(const short8v*)(sH + slot * 8);
    }
  }
  if (NORM_A) {
    const float cnt = cntPtr ? fmaxf(cntPtr[0], 1.f) : (float)nrows;
    compute_ss_lds(statsIn, gN, beN, cnt, ssS);
  }

  // ---- prefetch all A fragments ----
  const int row0 = rowBase + w * 32 + lr;
  const int row1 = row0 + 16;
  const bool ok0 = row0 < nrows, ok1 = row1 < nrows;
  const short8v szero = {0, 0, 0, 0, 0, 0, 0, 0};
  const ushort* aP0 = A + (size_t)row0 * 128 + lg * 8;
  const ushort* aP1 = A + (size_t)row1 * 128 + lg * 8;
  short8v ar0[4], ar1[4];
#pragma unroll
  for (int c = 0; c < 4; ++c) {
    ar0[c] = ok0 ? *(const short8v*)(aP0 + c * 32) : szero;
    ar1[c] = ok1 ? *(const short8v*)(aP1 + c * 32) : szero;
  }
  __syncthreads();

  const f32x4 fzero = {0.f, 0.f, 0.f, 0.f};
  f32x4 acc[2][4];
#pragma unroll
  for (int i = 0; i < 2; ++i)
#pragma unroll
    for (int j = 0; j < 4; ++j) acc[i][j] = fzero;

  const char* BhB = (const char*)Bh;
  __builtin_amdgcn_s_setprio(1);
#pragma unroll
  for (int c = 0; c < 4; ++c) {
    short8v a0 = ar0[c], a1 = ar1[c];
    if (NORM_A) {
      const int kb = c * 32 + lg * 8;
      const float4 s0 = *(const float4*)&ssS[kb];
      const float4 s1 = *(const float4*)&ssS[kb + 4];
      const float4 h0 = *(const float4*)&ssS[128 + kb];
      const float4 h1 = *(const float4*)&ssS[128 + kb + 4];
      const float sv[8] = {s0.x, s0.y, s0.z, s0.w, s1.x, s1.y, s1.z, s1.w};
      const float hv[8] = {h0.x, h0.y, h0.z, h0.w, h1.x, h1.y, h1.z, h1.w};
#pragma unroll
      for (int j = 0; j < 8; ++j) {
        a0[j] = (short)bf_hi(fmaxf(fmaf(bf_f((ushort)a0[j]), sv[j], hv[j]), 0.f));
        a1[j] = (short)bf_hi(fmaxf(fmaf(bf_f((ushort)a1[j]), sv[j], hv[j]), 0.f));
      }
    }
#pragma unroll
    for (int nf = 0; nf < 4; ++nf) {
      const int brow = nf * 16 + lr;
      const int off = (brow * 256 + (c * 4 + lg) * 16) ^ ((lr & 7) << 4);
      const short8v bh = *(const short8v*)(BhB + off);
      acc[0][nf] = __builtin_amdgcn_mfma_f32_16x16x32_bf16(a0, bh, acc[0][nf], 0, 0, 0);
      acc[1][nf] = __builtin_amdgcn_mfma_f32_16x16x32_bf16(a1, bh, acc[1][nf], 0, 0, 0);
    }
  }
  __builtin_amdgcn_s_setprio(0);

  // ---- epilogue: acc -> LDS bounce; stats partials ----
  float mrow[2][4];
#pragma unroll
  for (int mf = 0; mf < 2; ++mf)
#pragma unroll
    for (int rr = 0; rr < 4; ++rr) {
      const int row = rowBase + w * 32 + mf * 16 + lg * 4 + rr;
      float m = 0.f;
      if (row < nrows) m = MASKED ? ((tmask[row] > 0) ? 1.f : 0.f) : 1.f;
      mrow[mf][rr] = m;
    }
  __syncthreads();  // all waves done reading B
  ushort* Cs = SB;                      // [128][72]
  float* Sred = (float*)(SB + 9216);    // [4][64]
  float* Sq = Sred + 256;               // [4][64]
#pragma unroll
  for (int nf = 0; nf < 4; ++nf) {
    const int col = nf * 16 + lr;
    const float bcol = bias[cBase + col];
    float ps = 0.f, pq = 0.f;
#pragma unroll
    for (int mf = 0; mf < 2; ++mf) {
      const f32x4 vv = acc[mf][nf];
#pragma unroll
      for (int rr = 0; rr < 4; ++rr) {
        const float o = vv[rr] + bcol;
        const int rl = w * 32 + mf * 16 + lg * 4 + rr;
        Cs[rl * 72 + col] = bf_hi(o);
        const float mo = mrow[mf][rr] * o;
        ps += mo;
        pq += mo * o;
      }
    }
    ps += __shfl_xor(ps, 16);
    ps += __shfl_xor(ps, 32);
    pq += __shfl_xor(pq, 16);
    pq += __shfl_xor(pq, 32);
    if (lg == 0) {
      Sred[w * 64 + col] = ps;
      Sq[w * 64 + col] = pq;
    }
  }
  __syncthreads();
  {
    const int rl = tid >> 1, half = tid & 1;
    const int grow = rowBase + rl;
    if (grow < nrows) {
      ushort* dstp = C + (size_t)grow * 128 + cBase + half * 32;
      const ushort* srcp = Cs + rl * 72 + half * 32;
#pragma unroll
      for (int j = 0; j < 4; ++j)
        *(short8v*)(dstp + j * 8) = *(const short8v*)(srcp + j * 8);
    }
  }
  if (tid < 64) {
    float s = 0.f;
#pragma unroll
    for (int q = 0; q < 4; ++q) s += Sred[q * 64 + tid];
    atomicAdd(&statsOut[rep * 512 + cBase + tid], s);
  } else if (tid < 128) {
    float s = 0.f;
#pragma unroll
    for (int q = 0; q < 4; ++q) s += Sq[q * 64 + tid - 64];
    atomicAdd(&statsOut[rep * 512 + 256 + cBase + tid - 64], s);
  }
}

// ---------------------------------------------------------------------------
// FUSED agg+GEMM1, full-width 128x128 tile, single-bf16 B (32KB), grid 782.
// ---------------------------------------------------------------------------
__global__ __launch_bounds__(256, 4) void gemm_agg(
    const ushort* __restrict__ x, const ushort* __restrict__ feat,
    const int* __restrict__ offs, const int2* __restrict__ pairs,
    const float* __restrict__ deps, int layer, const ushort* __restrict__ WTh,
    const float* __restrict__ bias, ushort* __restrict__ C,
    float* __restrict__ statsOut, int* __restrict__ tmask, int nrows) {
  __shared__ ushort SB[19456];  // Bh[16384]; reuse: Cs[128][136] + red[2048]
  ushort* Bh = SB;
  const int tid = threadIdx.x;
  const int w = tid >> 6, lane = tid & 63, lr = lane & 15, lg = lane >> 4;
  const int rowBase = blockIdx.x * 128;
  const int rep = blockIdx.x & (NREP - 1);

  // ---- stage B once (128 cols x 128 k, swizzled) ----
  {
    const int cc = tid >> 1;   // col
    const int half = tid & 1;  // k half
    const ushort* sH = WTh + (size_t)cc * 128 + half * 64;
    char* BhB = (char*)Bh;
#pragma unroll
    for (int i = 0; i < 8; ++i) {
      const int slot = half * 8 + i;
      const int off = (cc * 256 + slot * 16) ^ ((cc & 7) << 4);
      *(short8v*)(BhB + off) = *(const short8v*)(sH + i * 8);
    }
  }

  const float ce = 1.f + deps[layer];
  const int row0 = rowBase + w * 32 + lr;
  const int row1 = row0 + 16;
  int o0a = 0, o1a = 0, o0b = 0, o1b = 0;
  if (row0 < nrows) {
    o0a = offs[layer * Nn + row0];
    o1a = offs[layer * Nn + row0 + 1];
  }
  if (row1 < nrows) {
    o0b = offs[layer * Nn + row1];
    o1b = offs[layer * Nn + row1 + 1];
  }
  if (lg == 0) {
    if (row0 < nrows) tmask[row0] = (o1a > o0a) ? 1 : 0;
    if (row1 < nrows) tmask[row1] = (o1b > o0b) ? 1 : 0;
  }

  short8v ar0[4], ar1[4];
  // row0 fragments
  {
    float a[4][8];
#pragma unroll
    for (int c = 0; c < 4; ++c)
#pragma unroll
      for (int j = 0; j < 8; ++j) a[c][j] = 0.f;
    for (int p = o0a; p < o1a; ++p) {
      const int2 pr = pairs[p];
      const float wgt = __int_as_float(pr.y);
      const ushort* xr = x + (size_t)pr.x * 128 + lg * 8;
#pragma unroll
      for (int c = 0; c < 4; ++c) {
        const short8v xv = *(const short8v*)(xr + c * 32);
#pragma unroll
        for (int j = 0; j < 8; ++j)
          a[c][j] = fmaf(wgt, bf_f((ushort)xv[j]), a[c][j]);
      }
    }
    if (o1a > o0a) {
      const ushort* fr = feat + (size_t)row0 * 128 + lg * 8;
#pragma unroll
      for (int c = 0; c < 4; ++c) {
        const short8v fv = *(const short8v*)(fr + c * 32);
#pragma unroll
        for (int j = 0; j < 8; ++j)
          a[c][j] = fmaf(ce, bf_f((ushort)fv[j]), a[c][j]);
      }
    }
#pragma unroll
    for (int c = 0; c < 4; ++c)
#pragma unroll
      for (int j = 0; j < 8; ++j) ar0[c][j] = (short)bf_hi(a[c][j]);
  }
  // row1 fragments
  {
    float a[4][8];
#pragma unroll
    for (int c = 0; c < 4; ++c)
#pragma unroll
      for (int j = 0; j < 8; ++j) a[c][j] = 0.f;
    for (int p = o0b; p < o1b; ++p) {
      const int2 pr = pairs[p];
      const float wgt = __int_as_float(pr.y);
      const ushort* xr = x + (size_t)pr.x * 128 + lg * 8;
#pragma unroll
      for (int c = 0; c < 4; ++c) {
        const short8v xv = *(const short8v*)(xr + c * 32);
#pragma unroll
        for (int j = 0; j < 8; ++j)
          a[c][j] = fmaf(wgt, bf_f((ushort)xv[j]), a[c][j]);
      }
    }
    if (o1b > o0b) {
      const ushort* fr = feat + (size_t)row1 * 128 + lg * 8;
#pragma unroll
      for (int c = 0; c < 4; ++c) {
        const short8v fv = *(const short8v*)(fr + c * 32);
#pragma unroll
        for (int j = 0; j < 8; ++j)
          a[c][j] = fmaf(ce, bf_f((ushort)fv[j]), a[c][j]);
      }
    }
#pragma unroll
    for (int c = 0; c < 4; ++c)
#pragma unroll
      for (int j = 0; j < 8; ++j) ar1[c][j] = (short)bf_hi(a[c][j]);
  }
  __syncthreads();

  const f32x4 fzero = {0.f, 0.f, 0.f, 0.f};
  f32x4 acc[2][8];
#pragma unroll
  for (int i = 0; i < 2; ++i)
#pragma unroll
    for (int j = 0; j < 8; ++j) acc[i][j] = fzero;

  const char* BhB = (const char*)Bh;
  __builtin_amdgcn_s_setprio(1);
#pragma unroll
  for (int c = 0; c < 4; ++c) {
    const short8v a0 = ar0[c], a1 = ar1[c];
#pragma unroll
    for (int nf = 0; nf < 8; ++nf) {
      const int brow = nf * 16 + lr;
      const int off = (brow * 256 + (c * 4 + lg) * 16) ^ ((lr & 7) << 4);
      const short8v bh = *(const short8v*)(BhB + off);
      acc[0][nf] = __builtin_amdgcn_mfma_f32_16x16x32_bf16(a0, bh, acc[0][nf], 0, 0, 0);
      acc[1][nf] = __builtin_amdgcn_mfma_f32_16x16x32_bf16(a1, bh, acc[1][nf], 0, 0, 0);
    }
  }
  __builtin_amdgcn_s_setprio(0);

  // ---- epilogue: mask via shfl of per-row deg flags ----
  const float dga = (o1a > o0a) ? 1.f : 0.f;
  const float dgb = (o1b > o0b) ? 1.f : 0.f;
  float mrow[2][4];
#pragma unroll
  for (int rr = 0; rr < 4; ++rr) {
    const int srcl = lg * 4 + rr;  // lane holding that row's deg flag
    mrow[0][rr] = __shfl(dga, srcl, 64);
    mrow[1][rr] = __shfl(dgb, srcl, 64);
  }
#pragma unroll
  for (int mf = 0; mf < 2; ++mf)
#pragma unroll
    for (int rr = 0; rr < 4; ++rr) {
      const int row = rowBase + w * 32 + mf * 16 + lg * 4 + rr;
      if (row >= nrows) mrow[mf][rr] = 0.f;
    }
  __syncthreads();
  ushort* Cs = SB;                     // [128][136]
  float* Sred = (float*)(SB + 17408);  // [4][128]
  float* Sq = Sred + 512;              // [4][128]
#pragma unroll
  for (int nf = 0; nf < 8; ++nf) {
    const int col = nf * 16 + lr;
    const float bcol = bias[col];
    float ps = 0.f, pq = 0.f;
#pragma unroll
    for (int mf = 0; mf < 2; ++mf) {
      const f32x4 vv = acc[mf][nf];
#pragma unroll
      for (int rr = 0; rr < 4; ++rr) {
        const float o = vv[rr] + bcol;
        const int rl = w * 32 + mf * 16 + lg * 4 + rr;
        Cs[rl * 136 + col] = bf_hi(o);
        const float mo = mrow[mf][rr] * o;
        ps += mo;
        pq += mo * o;
      }
    }
    ps += __shfl_xor(ps, 16);
    ps += __shfl_xor(ps, 32);
    pq += __shfl_xor(pq, 16);
    pq += __shfl_xor(pq, 32);
    if (lg == 0) {
      Sred[w * 128 + col] = ps;
      Sq[w * 128 + col] = pq;
    }
  }
  __syncthreads();
  {
    const int rl = tid >> 1, half = tid & 1;
    const int grow = rowBase + rl;
    if (grow < nrows) {
      ushort* dstp = C + (size_t)grow * 128 + half * 64;
      const ushort* srcp = Cs + rl * 136 + half * 64;
#pragma unroll
      for (int j = 0; j < 8; ++j)
        *(short8v*)(dstp + j * 8) = *(const short8v*)(srcp + j * 8);
    }
  }
  {
    const int col = tid & 127;
    float s = 0.f;
    if (tid < 128) {
#pragma unroll
      for (int q = 0; q < 4; ++q) s += Sred[q * 128 + col];
      atomicAdd(&statsOut[rep * 512 + col], s);
    } else {
#pragma unroll
      for (int q = 0; q < 4; ++q) s += Sq[q * 128 + col];
      atomicAdd(&statsOut[rep * 512 + 256 + col], s);
    }
  }
}

// ---------------------------------------------------------------------------
// GEMM #1: fp32 A (dag_x) rounded to bf16, single-bf16 B, K=64.
// ---------------------------------------------------------------------------
__global__ __launch_bounds__(256, 6) void gemm_f32a(
    const float* __restrict__ A, const ushort* __restrict__ WTh,
    const float* __restrict__ bias, ushort* __restrict__ C,
    float* __restrict__ statsOut, int nrows) {
  __shared__ ushort SB[10240];  // Bh[4096]; reused Cs[128][72] + red[1024]
  ushort* Bh = SB;
  const int tid = threadIdx.x;
  const int w = tid >> 6, lane = tid & 63, lr = lane & 15, lg = lane >> 4;
  const int rt = blockIdx.x >> 1, ct = blockIdx.x & 1;
  const int rowBase = rt * 128, cBase = ct * 64;
  const int rep = blockIdx.x & (NREP - 1);

  {
    const int cc = tid >> 2;
    const ushort* sH = WTh + (size_t)(cBase + cc) * 64;
    char* BhB = (char*)Bh;
#pragma unroll
    for (int i = 0; i < 2; ++i) {
      const int slot = (tid & 3) * 2 + i;
      const int off = (cc * 128 + slot * 16) ^ ((cc & 7) << 4);
      *(short8v*)(BhB + off) = *(const short8v*)(sH + slot * 8);
    }
  }

  const int row0 = rowBase + w * 32 + lr;
  const int row1 = row0 + 16;
  const bool ok0 = row0 < nrows, ok1 = row1 < nrows;
  const float4 fz4 = make_float4(0.f, 0.f, 0.f, 0.f);
  const float* aP0 = A + (size_t)row0 * 64 + lg * 8;
  const float* aP1 = A + (size_t)row1 * 64 + lg * 8;
  float4 ar0[2][2], ar1[2][2];
#pragma unroll
  for (int c = 0; c < 2; ++c) {
    ar0[c][0] = ok0 ? *(const float4*)(aP0 + c * 32) : fz4;
    ar0[c][1] = ok0 ? *(const float4*)(aP0 + c * 32 + 4) : fz4;
    ar1[c][0] = ok1 ? *(const float4*)(aP1 + c * 32) : fz4;
    ar1[c][1] = ok1 ? *(const float4*)(aP1 + c * 32 + 4) : fz4;
  }
  __syncthreads();

  const f32x4 fzero = {0.f, 0.f, 0.f, 0.f};
  f32x4 acc[2][4];
#pragma unroll
  for (int i = 0; i < 2; ++i)
#pragma unroll
    for (int j = 0; j < 4; ++j) acc[i][j] = fzero;

  const char* BhB = (const char*)Bh;
  __builtin_amdgcn_s_setprio(1);
#pragma unroll
  for (int c = 0; c < 2; ++c) {
    const float v0[8] = {ar0[c][0].x, ar0[c][0].y, ar0[c][0].z, ar0[c][0].w,
                         ar0[c][1].x, ar0[c][1].y, ar0[c][1].z, ar0[c][1].w};
    const float v1[8] = {ar1[c][0].x, ar1[c][0].y, ar1[c][0].z, ar1[c][0].w,
                         ar1[c][1].x, ar1[c][1].y, ar1[c][1].z, ar1[c][1].w};
    short8v a0, a1;
#pragma unroll
    for (int j = 0; j < 8; ++j) {
      a0[j] = (short)bf_hi(v0[j]);
      a1[j] = (short)bf_hi(v1[j]);
    }
#pragma unroll
    for (int nf = 0; nf < 4; ++nf) {
      const int brow = nf * 16 + lr;
      const int off = (brow * 128 + (c * 4 + lg) * 16) ^ ((lr & 7) << 4);
      const short8v bh = *(const short8v*)(BhB + off);
      acc[0][nf] = __builtin_amdgcn_mfma_f32_16x16x32_bf16(a0, bh, acc[0][nf], 0, 0, 0);
      acc[1][nf] = __builtin_amdgcn_mfma_f32_16x16x32_bf16(a1, bh, acc[1][nf], 0, 0, 0);
    }
  }
  __builtin_amdgcn_s_setprio(0);

  __syncthreads();
  ushort* Cs = SB;                    // [128][72]
  float* Sred = (float*)(SB + 9216);  // [4][64]
  float* Sq = Sred + 256;
#pragma unroll
  for (int nf = 0; nf < 4; ++nf) {
    const int col = nf * 16 + lr;
    const float bcol = bias[cBase + col];
    float ps = 0.f, pq = 0.f;
#pragma unroll
    for (int mf = 0; mf < 2; ++mf) {
      const f32x4 vv = acc[mf][nf];
#pragma unroll
      for (int rr = 0; rr < 4; ++rr) {
        const float o = vv[rr] + bcol;
        const int rl = w * 32 + mf * 16 + lg * 4 + rr;
        Cs[rl * 72 + col] = bf_hi(o);
        const int row = rowBase + rl;
        const float m = (row < nrows) ? 1.f : 0.f;
        const float mo = m * o;
        ps += mo;
        pq += mo * o;
      }
    }
    ps += __shfl_xor(ps, 16);
    ps += __shfl_xor(ps, 32);
    pq += __shfl_xor(pq, 16);
    pq += __shfl_xor(pq, 32);
    if (lg == 0) {
      Sred[w * 64 + col] = ps;
      Sq[w * 64 + col] = pq;
    }
  }
  __syncthreads();
  {
    const int rl = tid >> 1, half = tid & 1;
    const int grow = rowBase + rl;
    if (grow < nrows) {
      ushort* dstp = C + (size_t)grow * 128 + cBase + half * 32;
      const ushort* srcp = Cs + rl * 72 + half * 32;
#pragma unroll
      for (int j = 0; j < 4; ++j)
        *(short8v*)(dstp + j * 8) = *(const short8v*)(srcp + j * 8);
    }
  }
  if (tid < 64) {
    float s = 0.f;
#pragma unroll
    for (int q = 0; q < 4; ++q) s += Sred[q * 64 + tid];
    atomicAdd(&statsOut[rep * 512 + cBase + tid], s);
  } else if (tid < 128) {
    float s = 0.f;
#pragma unroll
    for (int q = 0; q < 4; ++q) s += Sq[q * 64 + tid - 64];
    atomicAdd(&statsOut[rep * 512 + 256 + cBase + tid - 64], s);
  }
}

// Weight transpose to bf16: 8 slots of 16384 ushorts ([col][K] row-major)
__global__ __launch_bounds__(256) void wsplit_kernel(
    const float* __restrict__ W1, const float* __restrict__ W2,
    const float* __restrict__ dW1, const float* __restrict__ dW2,
    ushort* __restrict__ wsT) {
  const int t = blockIdx.x * 256 + threadIdx.x;
  const int slot = t >> 14;
  const int idx = t & 16383;
  if (slot >= 8) return;
  const int Ks = (slot == 0) ? 64 : 128;
  if (idx >= 128 * Ks) return;
  const int c = idx / Ks;
  const int k = idx - c * Ks;
  float v;
  if (slot == 0) v = W1[k * 128 + c];
  else if (slot == 1) v = W2[k * 128 + c];
  else if (slot < 5) v = dW1[(slot - 2) * 16384 + k * 128 + c];
  else v = dW2[(slot - 5) * 16384 + k * 128 + c];
  wsT[slot * 16384 + c * Ks + k] = bf_hi(v);
}

// feat = relu(y*sc+sh); also zeroes x (replaces the xbuf memset dispatch).
__global__ __launch_bounds__(256) void normrelu_kernel(
    const ushort* __restrict__ in, const float* __restrict__ stats,
    const float* __restrict__ g, const float* __restrict__ be, float cntFixed,
    ushort* __restrict__ outp, ushort* __restrict__ xz) {
  __shared__ float ssS[256];
  compute_ss_lds(stats, g, be, cntFixed, ssS);
  __syncthreads();
  const int tid = threadIdx.x;
  const int c4 = (tid & 31) * 4;
  const float4 sc = *(const float4*)&ssS[c4];
  const float4 sh = *(const float4*)&ssS[128 + c4];
  const int rowBase = blockIdx.x * 64;
  const ushort4 z4 = make_ushort4(0, 0, 0, 0);
#pragma unroll
  for (int it = 0; it < 8; ++it) {
    const int row = rowBase + it * 8 + (tid >> 5);
    if (row >= Nn) continue;
    const size_t idx = (size_t)row * 32 + (tid & 31);
    const ushort4 v = ((const ushort4*)in)[idx];
    ushort4 o;
    o.x = bf_hi(fmaxf(fmaf(bf_f(v.x), sc.x, sh.x), 0.f));
    o.y = bf_hi(fmaxf(fmaf(bf_f(v.y), sc.y, sh.y), 0.f));
    o.z = bf_hi(fmaxf(fmaf(bf_f(v.z), sc.z, sh.z), 0.f));
    o.w = bf_hi(fmaxf(fmaf(bf_f(v.w), sc.w, sh.w), 0.f));
    ((ushort4*)outp)[idx] = o;
    ((ushort4*)xz)[idx] = z4;
  }
}

// x += (tmask>0) * relu(y*sc+sh)
__global__ __launch_bounds__(256) void normrelu_acc_kernel(
    const ushort* __restrict__ in, const float* __restrict__ stats,
    const float* __restrict__ g, const float* __restrict__ be,
    const float* __restrict__ cntPtr, const int* __restrict__ tmask,
    ushort* __restrict__ x) {
  __shared__ float ssS[256];
  compute_ss_lds(stats, g, be, fmaxf(cntPtr[0], 1.f), ssS);
  __syncthreads();
  const int tid = threadIdx.x;
  const int c4 = (tid & 31) * 4;
  const float4 sc = *(const float4*)&ssS[c4];
  const float4 sh = *(const float4*)&ssS[128 + c4];
  const int rowBase = blockIdx.x * 64;
#pragma unroll
  for (int it = 0; it < 8; ++it) {
    const int row = rowBase + it * 8 + (tid >> 5);
    if (row >= Nn || tmask[row] <= 0) continue;
    const size_t idx = (size_t)row * 32 + (tid & 31);
    const ushort4 v = ((const ushort4*)in)[idx];
    ushort4 xo = ((const ushort4*)x)[idx];
    xo.x = bf_hi(bf_f(xo.x) + fmaxf(fmaf(bf_f(v.x), sc.x, sh.x), 0.f));
    xo.y = bf_hi(bf_f(xo.y) + fmaxf(fmaf(bf_f(v.y), sc.y, sh.y), 0.f));
    xo.z = bf_hi(bf_f(xo.z) + fmaxf(fmaf(bf_f(v.z), sc.z, sh.z), 0.f));
    xo.w = bf_hi(bf_f(xo.w) + fmaxf(fmaf(bf_f(v.w), sc.w, sh.w), 0.f));
    ((ushort4*)x)[idx] = xo;
  }
}

__global__ __launch_bounds__(256) void scatter_leaves_kernel(
    const int* __restrict__ leaves, const ushort* __restrict__ feat,
    ushort* __restrict__ x, int nl) {
  const int gid = blockIdx.x * 256 + threadIdx.x;
  const int j = gid >> 5;
  if (j >= nl) return;
  const int node = leaves[j];
  const int c4 = (gid & 31) * 4;
  *(ushort4*)&x[(size_t)node * 128 + c4] =
      *(const ushort4*)&feat[(size_t)node * 128 + c4];
}

// ---------------- CSR build ----------------
__global__ __launch_bounds__(256) void deg_count_kernel(
    const int* __restrict__ dst, const int* __restrict__ lmask,
    int* __restrict__ cnts) {
  const int e = blockIdx.x * 256 + threadIdx.x;
  if (e >= Ee) return;
  atomicAdd(&cnts[lmask[e] * Nn + dst[e]], 1);
}

// scan1 + fused per-layer target count (nodes with deg>0) -> tcountf[0..2]
__global__ __launch_bounds__(256) void scan1_kernel(const int* __restrict__ in,
                                                    int* __restrict__ out,
                                                    int* __restrict__ bsum,
                                                    float* __restrict__ tcountf,
                                                    int n) {
  __shared__ int lds[256];
  __shared__ float tcS[3];
  const int tid = threadIdx.x;
  const int base = blockIdx.x * 2048 + tid * 8;
  int vals[8];
  int tsum = 0;
  float t0 = 0.f, t1 = 0.f, t2 = 0.f;
#pragma unroll
  for (int j = 0; j < 8; ++j) {
    const int i = base + j;
    const int v = (i < n) ? in[i] : 0;
    if (v > 0) {
      if (i < Nn) t0 += 1.f;
      else if (i < 2 * Nn) t1 += 1.f;
      else t2 += 1.f;
    }
    vals[j] = tsum;
    tsum += v;
  }
  lds[tid] = tsum;
  if (tid < 3) tcS[tid] = 0.f;
  __syncthreads();
  if (t0 != 0.f) atomicAdd(&tcS[0], t0);
  if (t1 != 0.f) atomicAdd(&tcS[1], t1);
  if (t2 != 0.f) atomicAdd(&tcS[2], t2);
  for (int off = 1; off < 256; off <<= 1) {
    const int y = (tid >= off) ? lds[tid - off] : 0;
    __syncthreads();
    lds[tid] += y;
    __syncthreads();
  }
  const int texcl = (tid > 0) ? lds[tid - 1] : 0;
#pragma unroll
  for (int j = 0; j < 8; ++j)
    if (base + j < n) out[base + j] = texcl + vals[j];
  if (tid == 255) bsum[blockIdx.x] = lds[255];
  __syncthreads();
  if (tid < 3 && tcS[tid] != 0.f) atomicAdd(&tcountf[tid], tcS[tid]);
}

// scan3 with scan2 fused: each block redundantly scans the 147 block sums.
__global__ __launch_bounds__(256) void scan3_kernel(int* __restrict__ out,
                                                    int* __restrict__ cursor,
                                                    const int* __restrict__ bsum,
                                                    int nb, int n, int etot) {
  __shared__ int bs[256];
  const int tid = threadIdx.x;
  const int v = (tid < nb) ? bsum[tid] : 0;
  bs[tid] = v;
  __syncthreads();
  for (int off = 1; off < 256; off <<= 1) {
    const int y = (tid >= off) ? bs[tid - off] : 0;
    __syncthreads();
    bs[tid] += y;
    __syncthreads();
  }
  const int i = blockIdx.x * 256 + tid;
  if (i >= n) return;
  const int b = i >> 11;
  const int excl = (b > 0) ? bs[b - 1] : 0;
  const int val = out[i] + excl;
  out[i] = val;
  cursor[i] = val;
  if (i == n - 1) out[n] = etot;
}

__global__ __launch_bounds__(256) void csr_fill_kernel(
    const int* __restrict__ src, const int* __restrict__ dst,
    const float* __restrict__ mult, const int* __restrict__ lmask,
    int* __restrict__ cursor, int2* __restrict__ pairs) {
  const int e = blockIdx.x * 256 + threadIdx.x;
  if (e >= Ee) return;
  const int slot = atomicAdd(&cursor[lmask[e] * Nn + dst[e]], 1);
  pairs[slot] = make_int2(src[e], __float_as_int(mult[e]));
}

// ---------------- readout: replicated-bucket counting-sort pool -----------
__global__ __launch_bounds__(256) void phist_kernel(const int* __restrict__ ridx,
                                                    const int* __restrict__ batch,
                                                    int* __restrict__ cnt, int n) {
  const int i = blockIdx.x * 256 + threadIdx.x;
  if (i >= n) return;
  atomicAdd(&cnt[batch[ridx[i]] * PR + (i & (PR - 1))], 1);
}

// exclusive scan over 256*PR = 8192 buckets (single block, 32 elems/thread)
__global__ void pscan_kernel(int* __restrict__ cnt, int* __restrict__ cur) {
  __shared__ int l[256];
  const int t = threadIdx.x;
  const int base = t * 32;
  int vals[32];
  int tsum = 0;
#pragma unroll
  for (int j = 0; j < 32; ++j) {
    const int v = cnt[base + j];
    vals[j] = tsum;
    tsum += v;
  }
  l[t] = tsum;
  __syncthreads();
  for (int off = 1; off < 256; off <<= 1) {
    const int y = (t >= off) ? l[t - off] : 0;
    __syncthreads();
    l[t] += y;
    __syncthreads();
  }
  const int excl = (t > 0) ? l[t - 1] : 0;
#pragma unroll
  for (int j = 0; j < 32; ++j) {
    const int v = excl + vals[j];
    cnt[base + j] = v;
    cur[base + j] = v;
  }
}

__global__ __launch_bounds__(256) void pfill_kernel(const int* __restrict__ ridx,
                                                    const int* __restrict__ batch,
                                                    int* __restrict__ cur,
                                                    int* __restrict__ sorted,
                                                    int n) {
  const int i = blockIdx.x * 256 + threadIdx.x;
  if (i >= n) return;
  const int node = ridx[i];
  const int slot = atomicAdd(&cur[batch[node] * PR + (i & (PR - 1))], 1);
  sorted[slot] = node;
}

// Parallel pool: 8 slices per graph -> Ppart[g*8+slice][128] (no atomics)
__global__ __launch_bounds__(256) void ppool_kernel(const int* __restrict__ sorted,
                                                    const int* __restrict__ offs,
                                                    const ushort* __restrict__ x,
                                                    float* __restrict__ Ppart,
                                                    int n) {
  __shared__ float part[4][256];
  const int bid = blockIdx.x;
  const int g = bid >> 3, slice = bid & (PSL - 1);
  const int w = threadIdx.x >> 6;
  const int lane = threadIdx.x & 63;
  const int o0 = offs[g * PR];
  const int o1 = (g < Gg - 1) ? offs[(g + 1) * PR] : n;
  float ax = 0.f, ay = 0.f;
  for (int p = o0 + slice * 4 + w; p < o1; p += 32) {
    const int node = sorted[p];
    const ushort2 xv = *(const ushort2*)&x[(size_t)node * 128 + lane * 2];
    ax += bf_f(xv.x);
    ay += bf_f(xv.y);
  }
  part[w][lane * 2] = ax;
  part[w][lane * 2 + 1] = ay;
  __syncthreads();
  if (threadIdx.x < 128) {
    const int c = threadIdx.x;
    Ppart[(size_t)bid * 128 + c] =
        part[0][c] + part[1][c] + part[2][c] + part[3][c];
  }
}

// Fused preduce + final linear: out[g][t] = 0.25*sum_slices(Ppart)@Wl + bl
__global__ __launch_bounds__(128) void pout_kernel(
    const float* __restrict__ Ppart, const float* __restrict__ Wl,
    const float* __restrict__ bl, float* __restrict__ out) {
  __shared__ float Pl[128];
  const int g = blockIdx.x;
  const int t = threadIdx.x;  // 128
  float s = 0.f;
#pragma unroll
  for (int r = 0; r < PSL; ++r) s += Ppart[(size_t)(g * PSL + r) * 128 + t];
  Pl[t] = s * 0.25f;
  __syncthreads();
  if (t < Tt) {
    float acc = 0.f;
    for (int c = 0; c < 128; ++c) acc += Pl[c] * Wl[c * Tt + t];
    out[g * Tt + t] = acc + bl[t];
  }
}

extern "C" void kernel_launch(void* const* d_in, const int* in_sizes, int n_in,
                              void* d_out, int out_size, void* d_ws,
                              size_t ws_size, hipStream_t stream) {
  const float* dag_x = (const float*)d_in[0];
  const int* eidx = (const int*)d_in[1];
  const int* src = eidx;
  const int* dst = eidx + Ee;
  const float* mult = (const float*)d_in[2];
  const int* lmask = (const int*)d_in[3];
  const int* batch = (const int*)d_in[4];
  const int* leaves = (const int*)d_in[5];
  const int* readouts = (const int*)d_in[6];
  const float* W1 = (const float*)d_in[7];
  const float* b1 = (const float*)d_in[8];
  const float* g1 = (const float*)d_in[9];
  const float* be1 = (const float*)d_in[10];
  const float* W2 = (const float*)d_in[11];
  const float* b2 = (const float*)d_in[12];
  const float* g2 = (const float*)d_in[13];
  const float* be2 = (const float*)d_in[14];
  const float* dW1 = (const float*)d_in[15];
  const float* db1 = (const float*)d_in[16];
  const float* dg1 = (const float*)d_in[17];
  const float* dbe1 = (const float*)d_in[18];
  const float* dW2 = (const float*)d_in[19];
  const float* db2 = (const float*)d_in[20];
  const float* dg2 = (const float*)d_in[21];
  const float* dbe2 = (const float*)d_in[22];
  const float* deps = (const float*)d_in[23];
  const float* Wl = (const float*)d_in[24];
  const float* bl = (const float*)d_in[25];
  float* out = (float*)d_out;

  const size_t ND = (size_t)Nn * Dd;
  ushort* feat = (ushort*)d_ws;           // ND bf16
  ushort* xbuf = feat + ND;               // ND bf16
  ushort* Abuf = xbuf + ND;               // ND bf16
  ushort* Bbuf = Abuf + ND;               // ND bf16 (gemm ping-pong)
  float* statsAll = (float*)(Bbuf + ND);  // 8 slots x [16][512]
  float* tcountf = statsAll + 8 * 8192;   // 8 (4 used) -- adjacent for memset
  int* tmask = (int*)(tcountf + 8);       // N
  ushort* wsT = (ushort*)(tmask + Nn);    // 131072 (8 bf16 weight slots)
  int* offs = (int*)(wsT + 131072);       // 3N+4
  int2* pairs = (int2*)(offs + 3 * Nn + 4);  // E pairs (src, mult)

  // transient overlays (xbuf region before it's initialized):
  int* cnts = (int*)xbuf;                 // 3N
  int* cursor = cnts + 3 * Nn;            // 3N
  int* bsum = cursor + 3 * Nn;            // 147
  const int nridx = in_sizes[6];          // 80000
  const int nleaves = in_sizes[5];        // 50000
  // pool overlays (Abuf dead by readout):
  int* pcnt = (int*)Abuf;                 // 256*PR (becomes offsets)
  int* pcur = pcnt + Gg * PR;             // 256*PR
  int* sorted = pcur + Gg * PR;           // nridx
  float* Ppart = (float*)(sorted + nridx);  // 2048*128

  dim3 blk(256);
  hipMemsetAsync(statsAll, 0, (8 * 8192 + 8) * sizeof(float), stream);
  wsplit_kernel<<<512, blk, 0, stream>>>(W1, W2, dW1, dW2, wsT);

  // ---- CSR build (tcount fused into scan1; scan2 fused into scan3) ----
  hipMemsetAsync(cnts, 0, 3 * Nn * sizeof(int), stream);
  deg_count_kernel<<<2344, blk, 0, stream>>>(dst, lmask, cnts);
  scan1_kernel<<<147, blk, 0, stream>>>(cnts, offs, bsum, tcountf, 3 * Nn);
  scan3_kernel<<<1172, blk, 0, stream>>>(offs, cursor, bsum, 147, 3 * Nn, Ee);
  csr_fill_kernel<<<2344, blk, 0, stream>>>(src, dst, mult, lmask, cursor, pairs);

  const int gGemm = 782 * 2;
  // ---- node feature transform ----
  gemm_f32a<<<gGemm, blk, 0, stream>>>(dag_x, wsT + 0 * 16384, b1, Abuf,
                                       statsAll + 0 * 8192, Nn);
  gemm_bf16<true, false><<<gGemm, blk, 0, stream>>>(
      Abuf, wsT + 1 * 16384, b2, statsAll + 0 * 8192, g1, be1, nullptr,
      nullptr, Bbuf, statsAll + 1 * 8192, Nn);
  // feat = relu(bn(y2)); also zeroes xbuf (no memset dispatch)
  normrelu_kernel<<<1563, blk, 0, stream>>>(Bbuf, statsAll + 1 * 8192, g2, be2,
                                            (float)Nn, feat, xbuf);
  scatter_leaves_kernel<<<6250, blk, 0, stream>>>(leaves, feat, xbuf, nleaves);

  // ---- DAG layers (agg fused into gemm1; full-width 128x128 tile) ----
  for (int layer = 0; layer < Ll; ++layer) {
    const int po = layer * Dd;
    float* st1 = statsAll + (size_t)(2 + 2 * layer) * 8192;
    float* st2 = statsAll + (size_t)(3 + 2 * layer) * 8192;
    gemm_agg<<<782, blk, 0, stream>>>(xbuf, feat, offs, pairs, deps, layer,
                                      wsT + (2 + layer) * 16384, db1 + po,
                                      Bbuf, st1, tmask, Nn);
    gemm_bf16<true, true><<<gGemm, blk, 0, stream>>>(
        Bbuf, wsT + (5 + layer) * 16384, db2 + po, st1, dg1 + po, dbe1 + po,
        tcountf + layer, tmask, Abuf, st2, Nn);
    normrelu_acc_kernel<<<1563, blk, 0, stream>>>(
        Abuf, st2, dg2 + po, dbe2 + po, tcountf + layer, tmask, xbuf);
  }

  // ---- readout (replicated-bucket counting sort, no float atomics) ----
  hipMemsetAsync(pcnt, 0, Gg * PR * sizeof(int), stream);
  const int gIdx = (nridx + 255) / 256;
  phist_kernel<<<gIdx, blk, 0, stream>>>(readouts, batch, pcnt, nridx);
  pscan_kernel<<<1, blk, 0, stream>>>(pcnt, pcur);
  pfill_kernel<<<gIdx, blk, 0, stream>>>(readouts, batch, pcur, sorted, nridx);
  ppool_kernel<<<Gg * PSL, blk, 0, stream>>>(sorted, pcnt, xbuf, Ppart, nridx);
  pout_kernel<<<Gg, dim3(128), 0, stream>>>(Ppart, Wl, bl, out);
}